// Round 2
// baseline (1177.611 us; speedup 1.0000x reference)
//
#include <hip/hip_runtime.h>
#include <hip/hip_bf16.h>

// Problem constants: B=8, S=2048, D=1024 (fp32 in/out).
static constexpr int S = 2048;
static constexpr int D = 1024;
static constexpr int NB = 8;

#define LOG2E 1.4426950408889634f

typedef float  f32x4  __attribute__((ext_vector_type(4)));
typedef __bf16 bf16x4 __attribute__((ext_vector_type(4)));
typedef __bf16 bf16x8 __attribute__((ext_vector_type(8)));

// GEMM tile config: 128x128 tile, BK=32 (one 16x16x32 MFMA K-step), 4 waves.
static constexpr int BM = 128;
static constexpr int BN = 128;
static constexpr int BK = 32;

#define AM_F32     0
#define AM_SOFTMAX 1
#define CM_PLAIN   0
#define CM_BIAS    1
#define CM_TRANSV  2

// ---------------------------------------------------------------------------
// NT split-bf16 GEMM: C[M][N] = A[M][K] * Bt[N][K]^T  (fp32 in, fp32 out)
// A-side optionally applies softmax (exp2((s-m)*log2e)*inv_l) during staging.
// C-side: plain store | +bias store | transposed store for V (Vt[b][d][s]).
// Split: x = hi + lo (bf16 each); product uses hi*hi + hi*lo + lo*hi.
// ---------------------------------------------------------------------------
template <int AMODE, int CMODE>
__global__ __launch_bounds__(256) void gemm_nt(
    const float* __restrict__ A, int lda, long sAz,
    const float* __restrict__ Bt, int ldb, long sBz,
    float* __restrict__ C, int ldc, long sCz,
    const float* __restrict__ bias,
    const float2* __restrict__ stats, long sStz,
    int K)
{
    // k-subtiled LDS: [ksub][row][8], +2 row pad => ksub stride 2080B (8-bank skew)
    __shared__ __bf16 Ah[4][BM + 2][8];
    __shared__ __bf16 Al[4][BM + 2][8];
    __shared__ __bf16 Bh[4][BN + 2][8];
    __shared__ __bf16 Bl[4][BN + 2][8];

    const int t = threadIdx.x;
    const int z = blockIdx.z;
    A += (long)z * sAz;
    Bt += (long)z * sBz;
    C += (long)z * sCz;

    const int m0 = blockIdx.y * BM;
    const int n0 = blockIdx.x * BN;

    // staging coords: thread t loads float4; quad id q = t + 256*i
    const int srow = t >> 3;          // 0..31 (+32*i)
    const int sc4  = (t & 7) * 4;     // f32 col 0..28
    const int sks  = (t & 7) >> 1;    // ksub 0..3
    const int sh   = (t & 1) * 4;     // elem offset in [8]

    // softmax row stats preload (rows fixed across K-loop)
    float2 st4[4];
    if (AMODE == AM_SOFTMAX) {
        const float2* stz = stats + (long)z * sStz;
#pragma unroll
        for (int i = 0; i < 4; ++i) st4[i] = stz[m0 + srow + 32 * i];
    }

    const int lane = t & 63, wid = t >> 6;
    const int wr = wid >> 1, wc = wid & 1;   // wave quadrant (2x2 of 64x64)
    const int fr = lane & 15, fq = lane >> 4;

    f32x4 acc[4][4] = {};

    const int ktiles = K / BK;
    for (int kt = 0; kt < ktiles; ++kt) {
        const int kb = kt * BK;
        __syncthreads();
        // ---- stage A tile (with optional softmax), split into hi/lo ----
#pragma unroll
        for (int i = 0; i < 4; ++i) {
            const int r = srow + 32 * i;
            f32x4 v = *(const f32x4*)(A + (long)(m0 + r) * lda + kb + sc4);
            if (AMODE == AM_SOFTMAX) {
                const float2 s = st4[i];
#pragma unroll
                for (int j = 0; j < 4; ++j)
                    v[j] = exp2f((v[j] - s.x) * LOG2E) * s.y;
            }
            bf16x4 h, l;
#pragma unroll
            for (int j = 0; j < 4; ++j) {
                __bf16 hh = (__bf16)v[j];
                h[j] = hh;
                l[j] = (__bf16)(v[j] - (float)hh);
            }
            *(bf16x4*)&Ah[sks][r][sh] = h;
            *(bf16x4*)&Al[sks][r][sh] = l;
        }
        // ---- stage B tile ----
#pragma unroll
        for (int i = 0; i < 4; ++i) {
            const int r = srow + 32 * i;
            f32x4 v = *(const f32x4*)(Bt + (long)(n0 + r) * ldb + kb + sc4);
            bf16x4 h, l;
#pragma unroll
            for (int j = 0; j < 4; ++j) {
                __bf16 hh = (__bf16)v[j];
                h[j] = hh;
                l[j] = (__bf16)(v[j] - (float)hh);
            }
            *(bf16x4*)&Bh[sks][r][sh] = h;
            *(bf16x4*)&Bl[sks][r][sh] = l;
        }
        __syncthreads();

        // ---- fragments + 3-term split MFMA ----
        bf16x8 ah[4], al[4], bh[4], bl[4];
#pragma unroll
        for (int mi = 0; mi < 4; ++mi) {
            const int r = wr * 64 + mi * 16 + fr;
            ah[mi] = *(const bf16x8*)&Ah[fq][r][0];
            al[mi] = *(const bf16x8*)&Al[fq][r][0];
        }
#pragma unroll
        for (int ni = 0; ni < 4; ++ni) {
            const int c = wc * 64 + ni * 16 + fr;
            bh[ni] = *(const bf16x8*)&Bh[fq][c][0];
            bl[ni] = *(const bf16x8*)&Bl[fq][c][0];
        }
#pragma unroll
        for (int mi = 0; mi < 4; ++mi)
#pragma unroll
            for (int ni = 0; ni < 4; ++ni) {
                acc[mi][ni] = __builtin_amdgcn_mfma_f32_16x16x32_bf16(
                    ah[mi], bh[ni], acc[mi][ni], 0, 0, 0);
                acc[mi][ni] = __builtin_amdgcn_mfma_f32_16x16x32_bf16(
                    ah[mi], bl[ni], acc[mi][ni], 0, 0, 0);
                acc[mi][ni] = __builtin_amdgcn_mfma_f32_16x16x32_bf16(
                    al[mi], bh[ni], acc[mi][ni], 0, 0, 0);
            }
    }

    // ---- epilogue ----
#pragma unroll
    for (int mi = 0; mi < 4; ++mi) {
        const int rbase = m0 + wr * 64 + mi * 16 + fq * 4;  // global row (4 consecutive)
#pragma unroll
        for (int ni = 0; ni < 4; ++ni) {
            const int col = n0 + wc * 64 + ni * 16 + fr;
            f32x4 a = acc[mi][ni];
            if (CMODE == CM_BIAS || CMODE == CM_TRANSV) {
                const float bv = bias[col];
#pragma unroll
                for (int j = 0; j < 4; ++j) a[j] += bv;
            }
            if (CMODE == CM_TRANSV) {
                // V projection: store transposed as Vt[b][d=col][s]
                const int b_ = rbase >> 11;        // 2048 rows per batch
                const int s_ = rbase & (S - 1);    // 16B-aligned (multiple of 4)
                *(f32x4*)(C + ((long)(b_ * D + col)) * S + s_) = a;
            } else {
#pragma unroll
                for (int j = 0; j < 4; ++j)
                    C[(long)(rbase + j) * ldc + col] = a[j];
            }
        }
    }
}

// ---------------------------------------------------------------------------
// Per-row softmax stats over score rows: stats[row] = (max, 1/sum(exp2((s-m)L)))
// one block (256 thr) per 2048-wide row
// ---------------------------------------------------------------------------
__global__ __launch_bounds__(256) void row_stats(
    const float* __restrict__ Sb, float2* __restrict__ stats)
{
    const long row = blockIdx.x;
    const float* p = Sb + row * (long)S;
    const int t = threadIdx.x;

    f32x4 x0 = *(const f32x4*)(p + t * 8);
    f32x4 x1 = *(const f32x4*)(p + t * 8 + 4);

    float m = -3.4e38f;
#pragma unroll
    for (int j = 0; j < 4; ++j) m = fmaxf(m, fmaxf(x0[j], x1[j]));
#pragma unroll
    for (int o = 32; o >= 1; o >>= 1) m = fmaxf(m, __shfl_xor(m, o));

    __shared__ float wm[4], wsum[4];
    const int wid = t >> 6, lane = t & 63;
    if (lane == 0) wm[wid] = m;
    __syncthreads();
    m = fmaxf(fmaxf(wm[0], wm[1]), fmaxf(wm[2], wm[3]));

    float ssum = 0.f;
#pragma unroll
    for (int j = 0; j < 4; ++j)
        ssum += exp2f((x0[j] - m) * LOG2E) + exp2f((x1[j] - m) * LOG2E);
#pragma unroll
    for (int o = 32; o >= 1; o >>= 1) ssum += __shfl_xor(ssum, o);
    if (lane == 0) wsum[wid] = ssum;
    __syncthreads();
    if (t == 0) {
        const float l = wsum[0] + wsum[1] + wsum[2] + wsum[3];
        stats[row] = make_float2(m, 1.0f / l);
    }
}

// ---------------------------------------------------------------------------
// 1024x1024 fp32 transpose (for W matrices): out[n][k] = in[k][n]
// ---------------------------------------------------------------------------
__global__ void transpose1024(const float* __restrict__ in, float* __restrict__ out)
{
    __shared__ float tile[32][33];
    const int bx = blockIdx.x * 32, by = blockIdx.y * 32;
    const int tx = threadIdx.x, ty = threadIdx.y;
#pragma unroll
    for (int i = ty; i < 32; i += 8) tile[i][tx] = in[(long)(by + i) * 1024 + bx + tx];
    __syncthreads();
#pragma unroll
    for (int i = ty; i < 32; i += 8) out[(long)(bx + i) * 1024 + by + tx] = tile[tx][i];
}

// ---------------------------------------------------------------------------
extern "C" void kernel_launch(void* const* d_in, const int* in_sizes, int n_in,
                              void* d_out, int out_size, void* d_ws, size_t ws_size,
                              hipStream_t stream)
{
    const float* X  = (const float*)d_in[0];  // [8,2048,1024]
    const float* Wq = (const float*)d_in[1];
    const float* bq = (const float*)d_in[2];
    const float* Wk = (const float*)d_in[3];
    const float* bk = (const float*)d_in[4];
    const float* Wv = (const float*)d_in[5];
    const float* bv = (const float*)d_in[6];
    float* out = (float*)d_out;
    char* ws = (char*)d_ws;

    // workspace layout
    const size_t WT_BYTES   = (size_t)3 * 1024 * 1024 * 4;       // 12 MB
    const size_t QKV_ONE    = (size_t)16384 * 1024 * 4;          // 64 MB
    const size_t BASE       = WT_BYTES + 3 * QKV_ONE;            // ~204 MB
    const size_t S_ONE      = (size_t)S * S * 4;                 // 16 MB / batch
    const size_t ST_ONE     = (size_t)S * sizeof(float2);        // 16 KB / batch

    int G = NB;  // batches per score-buffer group
    while (G > 1 && BASE + (size_t)G * (S_ONE + ST_ONE) > ws_size) G >>= 1;

    float* Wtq = (float*)ws;
    float* Wtk = Wtq + 1024 * 1024;
    float* Wtv = Wtk + 1024 * 1024;
    float* Q   = (float*)(ws + WT_BYTES);
    float* Kp  = Q + (size_t)16384 * 1024;
    float* Vt  = Kp + (size_t)16384 * 1024;          // [8][1024][2048]
    float* Sb  = (float*)(ws + BASE);                // [G][2048][2048]
    float2* stats = (float2*)(ws + BASE + (size_t)G * S_ONE);  // [G][2048]

    // 1) transpose weights
    dim3 tb(32, 8);
    transpose1024<<<dim3(32, 32), tb, 0, stream>>>(Wq, Wtq);
    transpose1024<<<dim3(32, 32), tb, 0, stream>>>(Wk, Wtk);
    transpose1024<<<dim3(32, 32), tb, 0, stream>>>(Wv, Wtv);

    // 2) projections: Q, K plain; V stored transposed per batch
    gemm_nt<AM_F32, CM_BIAS><<<dim3(D / BN, 16384 / BM, 1), 256, 0, stream>>>(
        X, D, 0, Wtq, D, 0, Q, D, 0, bq, nullptr, 0, D);
    gemm_nt<AM_F32, CM_BIAS><<<dim3(D / BN, 16384 / BM, 1), 256, 0, stream>>>(
        X, D, 0, Wtk, D, 0, Kp, D, 0, bk, nullptr, 0, D);
    gemm_nt<AM_F32, CM_TRANSV><<<dim3(D / BN, 16384 / BM, 1), 256, 0, stream>>>(
        X, D, 0, Wtv, D, 0, Vt, 0, 0, bv, nullptr, 0, D);

    // 3) per batch group: scores -> row stats -> PV (softmax fused into staging)
    for (int b0 = 0; b0 < NB; b0 += G) {
        gemm_nt<AM_F32, CM_PLAIN><<<dim3(S / BN, S / BM, G), 256, 0, stream>>>(
            Q + (size_t)b0 * S * D, D, (long)S * D,
            Kp + (size_t)b0 * S * D, D, (long)S * D,
            Sb, S, (long)S * S,
            nullptr, nullptr, 0, D);
        row_stats<<<dim3(G * S), 256, 0, stream>>>(Sb, stats);
        // PV contracts over the KEY axis: K = S (2048), NOT D.
        gemm_nt<AM_SOFTMAX, CM_PLAIN><<<dim3(D / BN, S / BM, G), 256, 0, stream>>>(
            Sb, S, (long)S * S,
            Vt + (size_t)b0 * D * S, S, (long)D * S,
            out + (size_t)b0 * S * D, D, (long)S * D,
            nullptr, stats, S, S);
    }
}

// Round 3
// 839.729 us; speedup vs baseline: 1.4024x; 1.4024x over previous
//
#include <hip/hip_runtime.h>
#include <hip/hip_bf16.h>

// B=8, S=2048, D=1024, fp32 in/out.
static constexpr int S = 2048;
static constexpr int D = 1024;
static constexpr int NB = 8;

#define LOG2E 1.4426950408889634f

typedef float  f32x4  __attribute__((ext_vector_type(4)));
typedef __bf16 bf16x4 __attribute__((ext_vector_type(4)));
typedef __bf16 bf16x8 __attribute__((ext_vector_type(8)));

#define CM_F32    0
#define CM_SPLIT  1
#define CM_TRANSV 2

__device__ __forceinline__ void gld_lds16(const void* g, void* l) {
    __builtin_amdgcn_global_load_lds(
        (const __attribute__((address_space(1))) void*)g,
        (__attribute__((address_space(3))) void*)l, 16, 0, 0);
}

// ---------------------------------------------------------------------------
// Pure-bf16 NT GEMM, 128x128 tile, 4 waves, global_load_lds staging.
// LDS row = 128 B = 8 chunks of 16 B.
//   TERMS==3: BK=32, chunks 0-3 = hi plane k[kb..kb+31], 4-7 = lo plane.
//             acc += Ah*Bh + Ah*Bl + Al*Bh   (split-bf16 fp32 emulation)
//   TERMS==1: BK=64, chunks 0-7 = k[kb..kb+63] single plane. acc += A*B (2 substeps)
// Swizzle (rule #21, both sides): LDS[row][slot] holds global chunk slot^(row&7).
//   stage:  chunk = (lane&7) ^ (lane>>3)   (row within 8-row group = lane>>3)
//   read :  slot  = wanted_chunk ^ (row&7)
// => ds_read_b128 per 64-lane wave touches all 32 banks 2-way (free).
// ---------------------------------------------------------------------------
template <int TERMS, int CMODE>
__global__ __launch_bounds__(256) void bgemm(
    const __bf16* __restrict__ Ah_, const __bf16* __restrict__ Al_, long sAz,
    const __bf16* __restrict__ Bh_, const __bf16* __restrict__ Bl_, long sBz,
    int lda, int ldb,
    void* __restrict__ C1, void* __restrict__ C2, int ldc, long sCz,
    const float* __restrict__ bias, int K)
{
    __shared__ __bf16 As[128][64];
    __shared__ __bf16 Bs[128][64];

    const int t = threadIdx.x;
    const int z = blockIdx.z;
    const int m0 = blockIdx.y * 128;
    const int n0 = blockIdx.x * 128;
    const int lane = t & 63, wid = t >> 6;
    const int wr = wid >> 1, wc = wid & 1;
    const int fr = lane & 15, fq = lane >> 4;
    const int srow = lane >> 3;                 // 0..7 row within 8-row group
    const int schunk = (lane & 7) ^ srow;       // swizzled source chunk

    const __bf16* Ahz = Ah_ + (long)z * sAz;
    const __bf16* Alz = (TERMS == 3) ? Al_ + (long)z * sAz : nullptr;
    const __bf16* Bhz = Bh_ + (long)z * sBz;
    const __bf16* Blz = (TERMS == 3) ? Bl_ + (long)z * sBz : nullptr;

    constexpr int BK = (TERMS == 3) ? 32 : 64;
    const int ksteps = K / BK;

    f32x4 acc[4][4] = {};

    for (int kt = 0; kt < ksteps; ++kt) {
        const int kb = kt * BK;
        __syncthreads();
        // ---- stage A (16 KB) + B (16 KB): 8 gld_lds per wave ----
#pragma unroll
        for (int j = 0; j < 4; ++j) {
            const int r = wid * 32 + j * 8 + srow;
            const __bf16* g;
            if (TERMS == 3)
                g = (schunk < 4) ? (Ahz + (long)(m0 + r) * lda + kb + schunk * 8)
                                 : (Alz + (long)(m0 + r) * lda + kb + (schunk - 4) * 8);
            else
                g = Ahz + (long)(m0 + r) * lda + kb + schunk * 8;
            gld_lds16(g, &As[wid * 32 + j * 8][0]);
        }
#pragma unroll
        for (int j = 0; j < 4; ++j) {
            const int r = wid * 32 + j * 8 + srow;
            const __bf16* g;
            if (TERMS == 3)
                g = (schunk < 4) ? (Bhz + (long)(n0 + r) * ldb + kb + schunk * 8)
                                 : (Blz + (long)(n0 + r) * ldb + kb + (schunk - 4) * 8);
            else
                g = Bhz + (long)(n0 + r) * ldb + kb + schunk * 8;
            gld_lds16(g, &Bs[wid * 32 + j * 8][0]);
        }
        __syncthreads();

        // ---- fragments: chunk fq (hi / ks0) and 4+fq (lo / ks1) ----
        bf16x8 a0[4], a1[4], b0[4], b1[4];
#pragma unroll
        for (int mi = 0; mi < 4; ++mi) {
            const int row = wr * 64 + mi * 16 + fr;
            const int r7 = row & 7;
            const char* base = (const char*)&As[row][0];
            a0[mi] = *(const bf16x8*)(base + ((fq ^ r7) << 4));
            a1[mi] = *(const bf16x8*)(base + (((4 + fq) ^ r7) << 4));
        }
#pragma unroll
        for (int ni = 0; ni < 4; ++ni) {
            const int row = wc * 64 + ni * 16 + fr;
            const int r7 = row & 7;
            const char* base = (const char*)&Bs[row][0];
            b0[ni] = *(const bf16x8*)(base + ((fq ^ r7) << 4));
            b1[ni] = *(const bf16x8*)(base + (((4 + fq) ^ r7) << 4));
        }

#pragma unroll
        for (int mi = 0; mi < 4; ++mi)
#pragma unroll
            for (int ni = 0; ni < 4; ++ni) {
                if (TERMS == 3) {
                    acc[mi][ni] = __builtin_amdgcn_mfma_f32_16x16x32_bf16(
                        a0[mi], b0[ni], acc[mi][ni], 0, 0, 0);  // hi*hi
                    acc[mi][ni] = __builtin_amdgcn_mfma_f32_16x16x32_bf16(
                        a0[mi], b1[ni], acc[mi][ni], 0, 0, 0);  // hi*lo
                    acc[mi][ni] = __builtin_amdgcn_mfma_f32_16x16x32_bf16(
                        a1[mi], b0[ni], acc[mi][ni], 0, 0, 0);  // lo*hi
                } else {
                    acc[mi][ni] = __builtin_amdgcn_mfma_f32_16x16x32_bf16(
                        a0[mi], b0[ni], acc[mi][ni], 0, 0, 0);  // k sub-step 0
                    acc[mi][ni] = __builtin_amdgcn_mfma_f32_16x16x32_bf16(
                        a1[mi], b1[ni], acc[mi][ni], 0, 0, 0);  // k sub-step 1
                }
            }
    }

    // ---- epilogue ----
#pragma unroll
    for (int mi = 0; mi < 4; ++mi) {
        const int rbase = m0 + wr * 64 + mi * 16 + fq * 4;
#pragma unroll
        for (int ni = 0; ni < 4; ++ni) {
            const int col = n0 + wc * 64 + ni * 16 + fr;
            f32x4 a = acc[mi][ni];
            if (CMODE == CM_SPLIT || CMODE == CM_TRANSV) {
                const float bv = bias[col];
#pragma unroll
                for (int j = 0; j < 4; ++j) a[j] += bv;
            }
            if (CMODE == CM_F32) {
                float* C = (float*)C1 + (long)z * sCz;
#pragma unroll
                for (int j = 0; j < 4; ++j)
                    C[(long)(rbase + j) * ldc + col] = a[j];
            } else if (CMODE == CM_SPLIT) {
                __bf16* Ch = (__bf16*)C1;
                __bf16* Cl = (__bf16*)C2;
#pragma unroll
                for (int j = 0; j < 4; ++j) {
                    const float q = a[j];
                    const __bf16 h = (__bf16)q;
                    Ch[(long)(rbase + j) * ldc + col] = h;
                    Cl[(long)(rbase + j) * ldc + col] = (__bf16)(q - (float)h);
                }
            } else {  // CM_TRANSV: Vt[b][col][s] bf16
                const int b_ = rbase >> 11;
                const int s_ = rbase & (S - 1);
                bf16x4 h;
#pragma unroll
                for (int j = 0; j < 4; ++j) h[j] = (__bf16)a[j];
                *(bf16x4*)((__bf16*)C1 + ((long)b_ * D + col) * S + s_) = h;
            }
        }
    }
}

// ---------------------------------------------------------------------------
// Split X into bf16 hi/lo planes.
// ---------------------------------------------------------------------------
__global__ __launch_bounds__(256) void xsplit(
    const float* __restrict__ X, __bf16* __restrict__ Xh, __bf16* __restrict__ Xl)
{
    const long i = ((long)blockIdx.x * 256 + threadIdx.x) * 4;
    f32x4 v = *(const f32x4*)(X + i);
    bf16x4 h, l;
#pragma unroll
    for (int j = 0; j < 4; ++j) {
        h[j] = (__bf16)v[j];
        l[j] = (__bf16)(v[j] - (float)h[j]);
    }
    *(bf16x4*)(Xh + i) = h;
    *(bf16x4*)(Xl + i) = l;
}

// ---------------------------------------------------------------------------
// Transpose 1024x1024 W and split into bf16 hi/lo planes. z selects matrix.
// ---------------------------------------------------------------------------
__global__ void wsplit(const float* __restrict__ W0, const float* __restrict__ W1,
                       const float* __restrict__ W2,
                       __bf16* __restrict__ Th, __bf16* __restrict__ Tl)
{
    const float* W = blockIdx.z == 0 ? W0 : (blockIdx.z == 1 ? W1 : W2);
    __bf16* th = Th + (long)blockIdx.z * 1024 * 1024;
    __bf16* tl = Tl + (long)blockIdx.z * 1024 * 1024;
    __shared__ float tile[32][33];
    const int bx = blockIdx.x * 32, by = blockIdx.y * 32;
    const int tx = threadIdx.x, ty = threadIdx.y;
#pragma unroll
    for (int i = ty; i < 32; i += 8) tile[i][tx] = W[(long)(by + i) * 1024 + bx + tx];
    __syncthreads();
#pragma unroll
    for (int i = ty; i < 32; i += 8) {
        const float v = tile[tx][i];
        const __bf16 h = (__bf16)v;
        th[(long)(bx + i) * 1024 + by + tx] = h;
        tl[(long)(bx + i) * 1024 + by + tx] = (__bf16)(v - (float)h);
    }
}

// ---------------------------------------------------------------------------
// Fused row softmax: per 2048-wide score row, compute max+sum then write
// P = exp(s-m)/l as bf16. One 256-thread block per row, row held in regs.
// ---------------------------------------------------------------------------
__global__ __launch_bounds__(256) void pconv(
    const float* __restrict__ Sb, __bf16* __restrict__ Pb)
{
    const long row = blockIdx.x;
    const float* p = Sb + row * (long)S;
    const int t = threadIdx.x;

    f32x4 x0 = *(const f32x4*)(p + t * 8);
    f32x4 x1 = *(const f32x4*)(p + t * 8 + 4);

    float m = -3.4e38f;
#pragma unroll
    for (int j = 0; j < 4; ++j) m = fmaxf(m, fmaxf(x0[j], x1[j]));
#pragma unroll
    for (int o = 32; o >= 1; o >>= 1) m = fmaxf(m, __shfl_xor(m, o));

    __shared__ float wm[4], wsum[4];
    const int wid = t >> 6, lane = t & 63;
    if (lane == 0) wm[wid] = m;
    __syncthreads();
    m = fmaxf(fmaxf(wm[0], wm[1]), fmaxf(wm[2], wm[3]));

    float e[8], ssum = 0.f;
#pragma unroll
    for (int j = 0; j < 4; ++j) {
        e[j]     = exp2f((x0[j] - m) * LOG2E);
        e[4 + j] = exp2f((x1[j] - m) * LOG2E);
        ssum += e[j] + e[4 + j];
    }
#pragma unroll
    for (int o = 32; o >= 1; o >>= 1) ssum += __shfl_xor(ssum, o);
    if (lane == 0) wsum[wid] = ssum;
    __syncthreads();
    const float invl = 1.0f / (wsum[0] + wsum[1] + wsum[2] + wsum[3]);

    bf16x8 out;
#pragma unroll
    for (int j = 0; j < 8; ++j) out[j] = (__bf16)(e[j] * invl);
    *(bf16x8*)(Pb + row * (long)S + t * 8) = out;
}

// ---------------------------------------------------------------------------
extern "C" void kernel_launch(void* const* d_in, const int* in_sizes, int n_in,
                              void* d_out, int out_size, void* d_ws, size_t ws_size,
                              hipStream_t stream)
{
    const float* X  = (const float*)d_in[0];
    const float* Wq = (const float*)d_in[1];
    const float* bq = (const float*)d_in[2];
    const float* Wk = (const float*)d_in[3];
    const float* bk = (const float*)d_in[4];
    const float* Wv = (const float*)d_in[5];
    const float* bv = (const float*)d_in[6];
    float* out = (float*)d_out;
    char* ws = (char*)d_ws;
    const size_t MB = 1u << 20;

    // layout (236 MB total):
    // [0,6)    Wthi[3] planes   [6,12)  Wtlo[3]
    // [12,76)  X region: Xhi|Xlo during projections; Sb(f32 2x16MB)|Pb(bf16 2x8MB) after
    // [76,108) Qhi  [108,140) Qlo  [140,172) Khi  [172,204) Klo  [204,236) Vt bf16
    __bf16* Wth = (__bf16*)ws;
    __bf16* Wtl = (__bf16*)(ws + 6 * MB);
    char*   xreg = ws + 12 * MB;
    __bf16* Xh = (__bf16*)xreg;
    __bf16* Xl = (__bf16*)(xreg + 32 * MB);
    __bf16* Qh = (__bf16*)(ws + 76 * MB);
    __bf16* Ql = (__bf16*)(ws + 108 * MB);
    __bf16* Kh = (__bf16*)(ws + 140 * MB);
    __bf16* Kl = (__bf16*)(ws + 172 * MB);
    __bf16* Vt = (__bf16*)(ws + 204 * MB);
    // reuse of X region once projections are done:
    float*  Sb = (float*)xreg;                   // [2][S][S] f32 (32 MB)
    __bf16* Pb = (__bf16*)(xreg + 32 * MB);      // [2][S][S] bf16 (16 MB)

    // 1) split inputs to bf16 hi/lo planes
    xsplit<<<dim3(16384), 256, 0, stream>>>(X, Xh, Xl);
    wsplit<<<dim3(32, 32, 3), dim3(32, 8), 0, stream>>>(Wq, Wk, Wv, Wth, Wtl);

    // 2) projections (3-term split GEMM); Q,K -> hi/lo planes, V -> transposed bf16
    const long MW = 1024 * 1024;
    bgemm<3, CM_SPLIT><<<dim3(D / 128, 16384 / 128, 1), 256, 0, stream>>>(
        Xh, Xl, 0, Wth, Wtl, 0, D, D, Qh, Ql, D, 0, bq, D);
    bgemm<3, CM_SPLIT><<<dim3(D / 128, 16384 / 128, 1), 256, 0, stream>>>(
        Xh, Xl, 0, Wth + MW, Wtl + MW, 0, D, D, Kh, Kl, D, 0, bk, D);
    bgemm<3, CM_TRANSV><<<dim3(D / 128, 16384 / 128, 1), 256, 0, stream>>>(
        Xh, Xl, 0, Wth + 2 * MW, Wtl + 2 * MW, 0, D, D, Vt, nullptr, 0, 0, bv, D);

    // 3) per 2-batch group: scores (3-term) -> fused softmax->bf16 P -> PV (1-term)
    for (int b0 = 0; b0 < NB; b0 += 2) {
        bgemm<3, CM_F32><<<dim3(S / 128, S / 128, 2), 256, 0, stream>>>(
            Qh + (long)b0 * S * D, Ql + (long)b0 * S * D, (long)S * D,
            Kh + (long)b0 * S * D, Kl + (long)b0 * S * D, (long)S * D,
            D, D, Sb, nullptr, S, (long)S * S, nullptr, D);
        pconv<<<dim3(2 * S), 256, 0, stream>>>(Sb, Pb);
        bgemm<1, CM_F32><<<dim3(D / 128, S / 128, 2), 256, 0, stream>>>(
            Pb, nullptr, (long)S * S,
            Vt + (long)b0 * D * S, nullptr, (long)D * S,
            S, S, out + (long)b0 * S * D, nullptr, D, (long)S * D, nullptr, S);
    }
}

// Round 4
// 667.799 us; speedup vs baseline: 1.7634x; 1.2575x over previous
//
#include <hip/hip_runtime.h>
#include <hip/hip_bf16.h>

// B=8, S=2048, D=1024, fp32 in/out.
static constexpr int S = 2048;
static constexpr int D = 1024;
static constexpr int NB = 8;

#define LOG2E 1.4426950408889634f

typedef float  f32x4  __attribute__((ext_vector_type(4)));
typedef __bf16 bf16x4 __attribute__((ext_vector_type(4)));
typedef __bf16 bf16x8 __attribute__((ext_vector_type(8)));

#define CM_F32    0
#define CM_SPLIT  1
#define CM_TRANSV 2

#define GLD16(g, l) __builtin_amdgcn_global_load_lds(                         \
    (const __attribute__((address_space(1))) void*)(g),                       \
    (__attribute__((address_space(3))) void*)(l), 16, 0, 0)

#define MFMA16(a, b, c) __builtin_amdgcn_mfma_f32_16x16x32_bf16((a), (b), (c), 0, 0, 0)

// ---------------------------------------------------------------------------
// 256x256 tile, 8 waves (2M x 4N), 4-phase pipelined K-loop, counted vmcnt.
//   TERMS==3: K-tile = 32 real k; slot0 = hi plane, slot1 = lo plane.
//             acc += Ah*Bh + Ah*Bl + Al*Bh   (split-bf16 fp32 emulation)
//   TERMS==1: K-tile = 64 k; slot = k-half.   acc += A*B
// LDS: A planes [2buf][2slot][256 rows][32 k] bf16 (16 KB each) then B planes.
// Staging: 4 stage-units per K-tile (A-s0, B-s0, A-s1, B-s1), 2 gload_lds each,
// issued one-per-phase for tile t+1 during tile t. Per-thread vmcnt queue =>
// wait vmcnt(6) at ph0/ph2 (steady), 4/0 on the last tile. Raw s_barrier only.
// ---------------------------------------------------------------------------
template <int TERMS, int CMODE>
__global__ __launch_bounds__(512, 1) void bgemm256(
    const __bf16* __restrict__ Ah_, const __bf16* __restrict__ Al_, long sAz,
    const __bf16* __restrict__ Bh_, const __bf16* __restrict__ Bl_, long sBz,
    int lda, int ldb,
    void* __restrict__ C1, void* __restrict__ C2, int ldc, long sCz,
    const float* __restrict__ bias, int K)
{
    extern __shared__ char smem[];   // 128 KiB dynamic
    char* const Abase = smem;
    char* const Bbase = smem + 65536;

    const int t = threadIdx.x;
    const int z = blockIdx.z;
    const int m0 = blockIdx.y * 256;
    const int n0 = blockIdx.x * 256;
    const int lane = t & 63, wid = t >> 6;
    const int wr = wid >> 2, wc = wid & 3;      // wave tile: 128 rows x 64 cols
    const int fr = lane & 15, fq = lane >> 4;
    const int srow = lane >> 2, schunk = lane & 3;   // staging lane coords

    const __bf16* Ahz = Ah_ + (long)z * sAz;
    const __bf16* Alz = (TERMS == 3) ? Al_ + (long)z * sAz : nullptr;
    const __bf16* Bhz = Bh_ + (long)z * sBz;
    const __bf16* Blz = (TERMS == 3) ? Bl_ + (long)z * sBz : nullptr;

    const int  ldsw  = wid * 1024;
    const long arow0 = (long)(m0 + wid * 16 + srow) * lda;
    const long arow1 = (long)(m0 + 128 + wid * 16 + srow) * lda;
    const long brow0 = (long)(n0 + wid * 16 + srow) * ldb;
    const long brow1 = (long)(n0 + 128 + wid * 16 + srow) * ldb;

    auto stA = [&](int tile, int s) {
        const long koff = (TERMS == 3) ? (long)tile * 32 + schunk * 8
                                       : (long)tile * 64 + s * 32 + schunk * 8;
        const __bf16* base = (TERMS == 3 && s) ? Alz : Ahz;
        char* lp = Abase + ((((tile & 1) << 1) | s) << 14) + ldsw;
        GLD16(base + arow0 + koff, lp);
        GLD16(base + arow1 + koff, lp + 8192);
    };
    auto stB = [&](int tile, int s) {
        const long koff = (TERMS == 3) ? (long)tile * 32 + schunk * 8
                                       : (long)tile * 64 + s * 32 + schunk * 8;
        const __bf16* base = (TERMS == 3 && s) ? Blz : Bhz;
        char* lp = Bbase + ((((tile & 1) << 1) | s) << 14) + ldsw;
        GLD16(base + brow0 + koff, lp);
        GLD16(base + brow1 + koff, lp + 8192);
    };
    auto rdA = [&](int buf, int s, int mi) -> bf16x8 {
        return *(const bf16x8*)(Abase + (((buf << 1) | s) << 14) +
                                (wr * 128 + mi * 16 + fr) * 64 + fq * 16);
    };
    auto rdB = [&](int buf, int s, int ni) -> bf16x8 {
        return *(const bf16x8*)(Bbase + (((buf << 1) | s) << 14) +
                                (wc * 64 + ni * 16 + fr) * 64 + fq * 16);
    };

    f32x4 acc[8][4] = {};
    const int ktiles = K / ((TERMS == 3) ? 32 : 64);

    // prologue: stage tile 0 (order must match in-loop issue order)
    stA(0, 0); stB(0, 0); stA(0, 1); stB(0, 1);

    for (int tt = 0; tt < ktiles; ++tt) {
        const int buf = tt & 1;
        const bool pf = (tt + 1 < ktiles);
        bf16x8 b0[4], b1[4], a[4], ah[4];

        // ---------------- phase 0: slot0, mi 0-3 ----------------
        if (pf) {
            stA(tt + 1, 0);
            asm volatile("s_waitcnt vmcnt(6)" ::: "memory");
        } else {
            asm volatile("s_waitcnt vmcnt(4)" ::: "memory");
        }
        __builtin_amdgcn_s_barrier();
#pragma unroll
        for (int ni = 0; ni < 4; ++ni) b0[ni] = rdB(buf, 0, ni);
#pragma unroll
        for (int mi = 0; mi < 4; ++mi) a[mi] = rdA(buf, 0, mi);
        __builtin_amdgcn_s_setprio(1);
#pragma unroll
        for (int mi = 0; mi < 4; ++mi)
#pragma unroll
            for (int ni = 0; ni < 4; ++ni)
                acc[mi][ni] = MFMA16(a[mi], b0[ni], acc[mi][ni]);
        __builtin_amdgcn_s_setprio(0);
        __builtin_amdgcn_s_barrier();

        // ---------------- phase 1: slot0, mi 4-7 ----------------
        if (pf) stB(tt + 1, 0);
#pragma unroll
        for (int mi = 0; mi < 4; ++mi) a[mi] = rdA(buf, 0, 4 + mi);
        __builtin_amdgcn_s_setprio(1);
#pragma unroll
        for (int mi = 0; mi < 4; ++mi)
#pragma unroll
            for (int ni = 0; ni < 4; ++ni)
                acc[4 + mi][ni] = MFMA16(a[mi], b0[ni], acc[4 + mi][ni]);
        __builtin_amdgcn_s_setprio(0);
        __builtin_amdgcn_s_barrier();

        // ---------------- phase 2: slot1, mi 0-3 ----------------
        if (pf) {
            stA(tt + 1, 1);
            asm volatile("s_waitcnt vmcnt(6)" ::: "memory");
        } else {
            asm volatile("s_waitcnt vmcnt(0)" ::: "memory");
        }
        __builtin_amdgcn_s_barrier();
#pragma unroll
        for (int ni = 0; ni < 4; ++ni) b1[ni] = rdB(buf, 1, ni);
#pragma unroll
        for (int mi = 0; mi < 4; ++mi) a[mi] = rdA(buf, 1, mi);
        if (TERMS == 3) {
#pragma unroll
            for (int mi = 0; mi < 4; ++mi) ah[mi] = rdA(buf, 0, mi);
        }
        __builtin_amdgcn_s_setprio(1);
#pragma unroll
        for (int mi = 0; mi < 4; ++mi)
#pragma unroll
            for (int ni = 0; ni < 4; ++ni) {
                if (TERMS == 3) {
                    acc[mi][ni] = MFMA16(ah[mi], b1[ni], acc[mi][ni]);  // hi*lo
                    acc[mi][ni] = MFMA16(a[mi], b0[ni], acc[mi][ni]);   // lo*hi
                } else {
                    acc[mi][ni] = MFMA16(a[mi], b1[ni], acc[mi][ni]);   // k-half 1
                }
            }
        __builtin_amdgcn_s_setprio(0);
        __builtin_amdgcn_s_barrier();

        // ---------------- phase 3: slot1, mi 4-7 ----------------
        if (pf) stB(tt + 1, 1);
#pragma unroll
        for (int mi = 0; mi < 4; ++mi) a[mi] = rdA(buf, 1, 4 + mi);
        if (TERMS == 3) {
#pragma unroll
            for (int mi = 0; mi < 4; ++mi) ah[mi] = rdA(buf, 0, 4 + mi);
        }
        __builtin_amdgcn_s_setprio(1);
#pragma unroll
        for (int mi = 0; mi < 4; ++mi)
#pragma unroll
            for (int ni = 0; ni < 4; ++ni) {
                if (TERMS == 3) {
                    acc[4 + mi][ni] = MFMA16(ah[mi], b1[ni], acc[4 + mi][ni]);
                    acc[4 + mi][ni] = MFMA16(a[mi], b0[ni], acc[4 + mi][ni]);
                } else {
                    acc[4 + mi][ni] = MFMA16(a[mi], b1[ni], acc[4 + mi][ni]);
                }
            }
        __builtin_amdgcn_s_setprio(0);
        __builtin_amdgcn_s_barrier();
    }

    // ---------------- epilogue ----------------
#pragma unroll
    for (int mi = 0; mi < 8; ++mi) {
        const int rbase = m0 + wr * 128 + mi * 16 + fq * 4;
#pragma unroll
        for (int ni = 0; ni < 4; ++ni) {
            const int col = n0 + wc * 64 + ni * 16 + fr;
            f32x4 a = acc[mi][ni];
            if (CMODE != CM_F32) {
                const float bv = bias[col];
#pragma unroll
                for (int j = 0; j < 4; ++j) a[j] += bv;
            }
            if (CMODE == CM_F32) {
                float* C = (float*)C1 + (long)z * sCz;
#pragma unroll
                for (int j = 0; j < 4; ++j)
                    C[(long)(rbase + j) * ldc + col] = a[j];
            } else if (CMODE == CM_SPLIT) {
                __bf16* Ch = (__bf16*)C1;
                __bf16* Cl = (__bf16*)C2;
#pragma unroll
                for (int j = 0; j < 4; ++j) {
                    const float q = a[j];
                    const __bf16 h = (__bf16)q;
                    Ch[(long)(rbase + j) * ldc + col] = h;
                    Cl[(long)(rbase + j) * ldc + col] = (__bf16)(q - (float)h);
                }
            } else {  // CM_TRANSV: Vt[b][col][s] bf16
                const int b_ = rbase >> 11;
                const int s_ = rbase & (S - 1);
                bf16x4 h;
#pragma unroll
                for (int j = 0; j < 4; ++j) h[j] = (__bf16)a[j];
                *(bf16x4*)((__bf16*)C1 + ((long)b_ * D + col) * S + s_) = h;
            }
        }
    }
}

// ---------------------------------------------------------------------------
// Split X into bf16 hi/lo planes.
// ---------------------------------------------------------------------------
__global__ __launch_bounds__(256) void xsplit(
    const float* __restrict__ X, __bf16* __restrict__ Xh, __bf16* __restrict__ Xl)
{
    const long i = ((long)blockIdx.x * 256 + threadIdx.x) * 4;
    f32x4 v = *(const f32x4*)(X + i);
    bf16x4 h, l;
#pragma unroll
    for (int j = 0; j < 4; ++j) {
        h[j] = (__bf16)v[j];
        l[j] = (__bf16)(v[j] - (float)h[j]);
    }
    *(bf16x4*)(Xh + i) = h;
    *(bf16x4*)(Xl + i) = l;
}

// ---------------------------------------------------------------------------
// Transpose 1024x1024 W and split into bf16 hi/lo planes. z selects matrix.
// ---------------------------------------------------------------------------
__global__ void wsplit(const float* __restrict__ W0, const float* __restrict__ W1,
                       const float* __restrict__ W2,
                       __bf16* __restrict__ Th, __bf16* __restrict__ Tl)
{
    const float* W = blockIdx.z == 0 ? W0 : (blockIdx.z == 1 ? W1 : W2);
    __bf16* th = Th + (long)blockIdx.z * 1024 * 1024;
    __bf16* tl = Tl + (long)blockIdx.z * 1024 * 1024;
    __shared__ float tile[32][33];
    const int bx = blockIdx.x * 32, by = blockIdx.y * 32;
    const int tx = threadIdx.x, ty = threadIdx.y;
#pragma unroll
    for (int i = ty; i < 32; i += 8) tile[i][tx] = W[(long)(by + i) * 1024 + bx + tx];
    __syncthreads();
#pragma unroll
    for (int i = ty; i < 32; i += 8) {
        const float v = tile[tx][i];
        const __bf16 h = (__bf16)v;
        th[(long)(bx + i) * 1024 + by + tx] = h;
        tl[(long)(bx + i) * 1024 + by + tx] = (__bf16)(v - (float)h);
    }
}

// ---------------------------------------------------------------------------
// Fused row softmax: read f32 score row, write P = exp(s-m)/l as bf16
// IN-PLACE into the start of the row's f32 storage.
// ---------------------------------------------------------------------------
__global__ __launch_bounds__(256) void pconv(float* __restrict__ Sb)
{
    const long row = blockIdx.x;
    float* p = Sb + row * (long)S;
    const int t = threadIdx.x;

    f32x4 x0 = *(const f32x4*)(p + t * 8);
    f32x4 x1 = *(const f32x4*)(p + t * 8 + 4);

    float m = -3.4e38f;
#pragma unroll
    for (int j = 0; j < 4; ++j) m = fmaxf(m, fmaxf(x0[j], x1[j]));
#pragma unroll
    for (int o = 32; o >= 1; o >>= 1) m = fmaxf(m, __shfl_xor(m, o));

    __shared__ float wm[4], wsum[4];
    const int wid = t >> 6, lane = t & 63;
    if (lane == 0) wm[wid] = m;
    __syncthreads();
    m = fmaxf(fmaxf(wm[0], wm[1]), fmaxf(wm[2], wm[3]));

    float e[8], ssum = 0.f;
#pragma unroll
    for (int j = 0; j < 4; ++j) {
        e[j]     = exp2f((x0[j] - m) * LOG2E);
        e[4 + j] = exp2f((x1[j] - m) * LOG2E);
        ssum += e[j] + e[4 + j];
    }
#pragma unroll
    for (int o = 32; o >= 1; o >>= 1) ssum += __shfl_xor(ssum, o);
    if (lane == 0) wsum[wid] = ssum;
    __syncthreads();
    const float invl = 1.0f / (wsum[0] + wsum[1] + wsum[2] + wsum[3]);

    bf16x8 outv;
#pragma unroll
    for (int j = 0; j < 8; ++j) outv[j] = (__bf16)(e[j] * invl);
    *(bf16x8*)((__bf16*)p + t * 8) = outv;
}

// ---------------------------------------------------------------------------
extern "C" void kernel_launch(void* const* d_in, const int* in_sizes, int n_in,
                              void* d_out, int out_size, void* d_ws, size_t ws_size,
                              hipStream_t stream)
{
    const float* X  = (const float*)d_in[0];
    const float* Wq = (const float*)d_in[1];
    const float* bq = (const float*)d_in[2];
    const float* Wk = (const float*)d_in[3];
    const float* bk = (const float*)d_in[4];
    const float* Wv = (const float*)d_in[5];
    const float* bv = (const float*)d_in[6];
    float* out = (float*)d_out;
    char* ws = (char*)d_ws;
    const size_t MB = 1u << 20;

    // layout (236 MB):
    // [0,6) Wth[3]  [6,12) Wtl[3]
    // [12,76) X region: Xh|Xl during projections; Sb f32 [4][S][S] after (P in-place)
    // [76,108) Qh  [108,140) Ql  [140,172) Kh  [172,204) Kl  [204,236) Vt bf16
    __bf16* Wth = (__bf16*)ws;
    __bf16* Wtl = (__bf16*)(ws + 6 * MB);
    char*   xreg = ws + 12 * MB;
    __bf16* Xh = (__bf16*)xreg;
    __bf16* Xl = (__bf16*)(xreg + 32 * MB);
    __bf16* Qh = (__bf16*)(ws + 76 * MB);
    __bf16* Ql = (__bf16*)(ws + 108 * MB);
    __bf16* Kh = (__bf16*)(ws + 140 * MB);
    __bf16* Kl = (__bf16*)(ws + 172 * MB);
    __bf16* Vt = (__bf16*)(ws + 204 * MB);
    float*  Sb = (float*)xreg;               // [4][S][S] f32; P bf16 in-place

    const int DYN_LDS = 131072;
    hipFuncSetAttribute(reinterpret_cast<const void*>(&bgemm256<3, CM_SPLIT>),
                        hipFuncAttributeMaxDynamicSharedMemorySize, DYN_LDS);
    hipFuncSetAttribute(reinterpret_cast<const void*>(&bgemm256<3, CM_TRANSV>),
                        hipFuncAttributeMaxDynamicSharedMemorySize, DYN_LDS);
    hipFuncSetAttribute(reinterpret_cast<const void*>(&bgemm256<3, CM_F32>),
                        hipFuncAttributeMaxDynamicSharedMemorySize, DYN_LDS);
    hipFuncSetAttribute(reinterpret_cast<const void*>(&bgemm256<1, CM_F32>),
                        hipFuncAttributeMaxDynamicSharedMemorySize, DYN_LDS);

    // 1) split inputs to bf16 hi/lo planes
    xsplit<<<dim3(16384), 256, 0, stream>>>(X, Xh, Xl);
    wsplit<<<dim3(32, 32, 3), dim3(32, 8), 0, stream>>>(Wq, Wk, Wv, Wth, Wtl);

    // 2) projections (3-term split GEMM)
    const long MW = 1024 * 1024;
    bgemm256<3, CM_SPLIT><<<dim3(D / 256, 16384 / 256, 1), 512, DYN_LDS, stream>>>(
        Xh, Xl, 0, Wth, Wtl, 0, D, D, Qh, Ql, D, 0, bq, D);
    bgemm256<3, CM_SPLIT><<<dim3(D / 256, 16384 / 256, 1), 512, DYN_LDS, stream>>>(
        Xh, Xl, 0, Wth + MW, Wtl + MW, 0, D, D, Kh, Kl, D, 0, bk, D);
    bgemm256<3, CM_TRANSV><<<dim3(D / 256, 16384 / 256, 1), 512, DYN_LDS, stream>>>(
        Xh, Xl, 0, Wth + 2 * MW, Wtl + 2 * MW, 0, D, D, Vt, nullptr, 0, 0, bv, D);

    // 3) per 4-batch group: scores -> in-place softmax->bf16 P -> PV
    for (int g = 0; g < 2; ++g) {
        const int b0 = g * 4;
        bgemm256<3, CM_F32><<<dim3(S / 256, S / 256, 4), 512, DYN_LDS, stream>>>(
            Qh + (long)b0 * S * D, Ql + (long)b0 * S * D, (long)S * D,
            Kh + (long)b0 * S * D, Kl + (long)b0 * S * D, (long)S * D,
            D, D, Sb, nullptr, S, (long)S * S, nullptr, D);
        pconv<<<dim3(4 * S), 256, 0, stream>>>(Sb);
        // PV: A = bf16 P rows embedded in f32 buffer (lda = 2S bf16 elements)
        bgemm256<1, CM_F32><<<dim3(D / 256, S / 256, 4), 512, DYN_LDS, stream>>>(
            (const __bf16*)Sb, nullptr, 2L * S * S,
            Vt + (long)b0 * D * S, nullptr, (long)D * S,
            2 * S, S, out + (long)b0 * S * D, nullptr, D, (long)S * D, nullptr, S);
    }
}

// Round 5
// 650.306 us; speedup vs baseline: 1.8109x; 1.0269x over previous
//
#include <hip/hip_runtime.h>
#include <hip/hip_bf16.h>

// B=8, S=2048, D=1024, fp32 in/out.
static constexpr int S = 2048;
static constexpr int D = 1024;
static constexpr int NB = 8;

#define LOG2E 1.4426950408889634f

typedef float  f32x4  __attribute__((ext_vector_type(4)));
typedef __bf16 bf16x4 __attribute__((ext_vector_type(4)));
typedef __bf16 bf16x8 __attribute__((ext_vector_type(8)));

#define CM_F32    0
#define CM_SPLIT  1
#define CM_TRANSV 2

#define GLD16(g, l) __builtin_amdgcn_global_load_lds(                         \
    (const __attribute__((address_space(1))) void*)(g),                       \
    (__attribute__((address_space(3))) void*)(l), 16, 0, 0)

#define MFMA16(a, b, c) __builtin_amdgcn_mfma_f32_16x16x32_bf16((a), (b), (c), 0, 0, 0)

// ---------------------------------------------------------------------------
// 256x256 tile, 8 waves (2M x 4N), 4-phase pipelined K-loop, counted vmcnt.
//   TERMS==3: K-tile = 32 real k; chunks 0-3 = hi plane, 4-7 = lo plane.
//             acc += Ah*Bh + Ah*Bl + Al*Bh   (split-bf16 fp32 emulation)
//   TERMS==1: K-tile = 64 k; chunks 0-7 = k 0..63.   acc += A*B
// LDS: per buf, A = 256 rows x 128 B, B same. Row packs both slots.
// Swizzle (rule #21, both sides, round-3-proven 0-conflict pattern):
//   LDS slot s of row r holds global chunk s^(r&7).
//   stage: lane reads global chunk (lane&7)^(lane>>3); gload_lds writes linear.
//   read : want chunk c of row r -> slot c^(r&7).
// Stage-units per K-tile: A-half0, A-half1, B-half0, B-half1 (2 gload_lds each),
// issued one per phase for tile t+1. All 4 units needed at ph0 -> wait vmcnt(2)
// at ph0 (8 tile-t loads retired, 2 prefetch in flight). Raw s_barrier only.
// ---------------------------------------------------------------------------
template <int TERMS, int CMODE>
__global__ __launch_bounds__(512, 1) void bgemm256(
    const __bf16* __restrict__ Ah_, const __bf16* __restrict__ Al_, long sAz,
    const __bf16* __restrict__ Bh_, const __bf16* __restrict__ Bl_, long sBz,
    int lda, int ldb,
    void* __restrict__ C1, void* __restrict__ C2, int ldc, long sCz,
    const float* __restrict__ bias, int K)
{
    extern __shared__ char smem[];   // 128 KiB: [buf][A 32K][buf at +32K]; B at +64K

    const int t = threadIdx.x;
    const int z = blockIdx.z;
    const int m0 = blockIdx.y * 256;
    const int n0 = blockIdx.x * 256;
    const int lane = t & 63, wid = t >> 6;
    const int wr = wid >> 2, wc = wid & 3;      // wave tile: 128 rows x 64 cols
    const int fr = lane & 15, fq = lane >> 4;
    const int srow = lane >> 3;                 // 0..7
    const int schunk = (lane & 7) ^ srow;       // swizzled global chunk 0..7
    const int rowbase = wid * 8 + srow;

    const __bf16* Ahz = Ah_ + (long)z * sAz;
    const __bf16* Alz = (TERMS == 3) ? Al_ + (long)z * sAz : nullptr;
    const __bf16* Bhz = Bh_ + (long)z * sBz;
    const __bf16* Blz = (TERMS == 3) ? Bl_ + (long)z * sBz : nullptr;

    auto stA = [&](int tile, int h) {
        const long kk = (TERMS == 3) ? (long)tile * 32 + (schunk & 3) * 8
                                     : (long)tile * 64 + schunk * 8;
        const __bf16* plane = (TERMS == 3 && schunk >= 4) ? Alz : Ahz;
        char* lbase = smem + (tile & 1) * 32768 + (h * 128 + wid * 8) * 128;
#pragma unroll
        for (int i = 0; i < 2; ++i)
            GLD16(plane + (long)(m0 + h * 128 + i * 64 + rowbase) * lda + kk,
                  lbase + i * 8192);
    };
    auto stB = [&](int tile, int h) {
        const long kk = (TERMS == 3) ? (long)tile * 32 + (schunk & 3) * 8
                                     : (long)tile * 64 + schunk * 8;
        const __bf16* plane = (TERMS == 3 && schunk >= 4) ? Blz : Bhz;
        char* lbase = smem + 65536 + (tile & 1) * 32768 + (h * 128 + wid * 8) * 128;
#pragma unroll
        for (int i = 0; i < 2; ++i)
            GLD16(plane + (long)(n0 + h * 128 + i * 64 + rowbase) * ldb + kk,
                  lbase + i * 8192);
    };
    auto rdA = [&](int buf, int c, int mi) -> bf16x8 {
        const int row = wr * 128 + mi * 16 + fr;
        return *(const bf16x8*)(smem + buf * 32768 + row * 128 +
                                ((c ^ (row & 7)) << 4));
    };
    auto rdB = [&](int buf, int c, int ni) -> bf16x8 {
        const int row = wc * 64 + ni * 16 + fr;
        return *(const bf16x8*)(smem + 65536 + buf * 32768 + row * 128 +
                                ((c ^ (row & 7)) << 4));
    };

    f32x4 acc[8][4] = {};
    const int ktiles = K / ((TERMS == 3) ? 32 : 64);

    // prologue: stage tile 0 fully (8 loads)
    stA(0, 0); stA(0, 1); stB(0, 0); stB(0, 1);

    for (int tt = 0; tt < ktiles; ++tt) {
        const int buf = tt & 1;
        const bool pf = (tt + 1 < ktiles);
        bf16x8 b0[4], b1[4], a[4], ah[4];

        // ---------------- phase 0: slot0 (chunk fq), mi 0-3 ----------------
        if (pf) {
            stA(tt + 1, 0);
            asm volatile("s_waitcnt vmcnt(2)" ::: "memory");
        } else {
            asm volatile("s_waitcnt vmcnt(0)" ::: "memory");
        }
        __builtin_amdgcn_s_barrier();
#pragma unroll
        for (int ni = 0; ni < 4; ++ni) b0[ni] = rdB(buf, fq, ni);
#pragma unroll
        for (int mi = 0; mi < 4; ++mi) a[mi] = rdA(buf, fq, mi);
        __builtin_amdgcn_s_setprio(1);
#pragma unroll
        for (int mi = 0; mi < 4; ++mi)
#pragma unroll
            for (int ni = 0; ni < 4; ++ni)
                acc[mi][ni] = MFMA16(a[mi], b0[ni], acc[mi][ni]);
        __builtin_amdgcn_s_setprio(0);
        __builtin_amdgcn_s_barrier();

        // ---------------- phase 1: slot0, mi 4-7 ----------------
        if (pf) stA(tt + 1, 1);
#pragma unroll
        for (int mi = 0; mi < 4; ++mi) a[mi] = rdA(buf, fq, 4 + mi);
        __builtin_amdgcn_s_setprio(1);
#pragma unroll
        for (int mi = 0; mi < 4; ++mi)
#pragma unroll
            for (int ni = 0; ni < 4; ++ni)
                acc[4 + mi][ni] = MFMA16(a[mi], b0[ni], acc[4 + mi][ni]);
        __builtin_amdgcn_s_setprio(0);
        __builtin_amdgcn_s_barrier();

        // ---------------- phase 2: slot1 (chunk 4+fq), mi 0-3 ----------------
        if (pf) stB(tt + 1, 0);
#pragma unroll
        for (int ni = 0; ni < 4; ++ni) b1[ni] = rdB(buf, 4 + fq, ni);
#pragma unroll
        for (int mi = 0; mi < 4; ++mi) a[mi] = rdA(buf, 4 + fq, mi);
        if (TERMS == 3) {
#pragma unroll
            for (int mi = 0; mi < 4; ++mi) ah[mi] = rdA(buf, fq, mi);
        }
        __builtin_amdgcn_s_setprio(1);
#pragma unroll
        for (int mi = 0; mi < 4; ++mi)
#pragma unroll
            for (int ni = 0; ni < 4; ++ni) {
                if (TERMS == 3) {
                    acc[mi][ni] = MFMA16(ah[mi], b1[ni], acc[mi][ni]);  // hi*lo
                    acc[mi][ni] = MFMA16(a[mi], b0[ni], acc[mi][ni]);   // lo*hi
                } else {
                    acc[mi][ni] = MFMA16(a[mi], b1[ni], acc[mi][ni]);   // k-half 1
                }
            }
        __builtin_amdgcn_s_setprio(0);
        __builtin_amdgcn_s_barrier();

        // ---------------- phase 3: slot1, mi 4-7 ----------------
        if (pf) stB(tt + 1, 1);
#pragma unroll
        for (int mi = 0; mi < 4; ++mi) a[mi] = rdA(buf, 4 + fq, 4 + mi);
        if (TERMS == 3) {
#pragma unroll
            for (int mi = 0; mi < 4; ++mi) ah[mi] = rdA(buf, fq, 4 + mi);
        }
        __builtin_amdgcn_s_setprio(1);
#pragma unroll
        for (int mi = 0; mi < 4; ++mi)
#pragma unroll
            for (int ni = 0; ni < 4; ++ni) {
                if (TERMS == 3) {
                    acc[4 + mi][ni] = MFMA16(ah[mi], b1[ni], acc[4 + mi][ni]);
                    acc[4 + mi][ni] = MFMA16(a[mi], b0[ni], acc[4 + mi][ni]);
                } else {
                    acc[4 + mi][ni] = MFMA16(a[mi], b1[ni], acc[4 + mi][ni]);
                }
            }
        __builtin_amdgcn_s_setprio(0);
        __builtin_amdgcn_s_barrier();
    }

    // ---------------- epilogue ----------------
#pragma unroll
    for (int mi = 0; mi < 8; ++mi) {
        const int rbase = m0 + wr * 128 + mi * 16 + fq * 4;
#pragma unroll
        for (int ni = 0; ni < 4; ++ni) {
            const int col = n0 + wc * 64 + ni * 16 + fr;
            f32x4 a = acc[mi][ni];
            if (CMODE != CM_F32) {
                const float bv = bias[col];
#pragma unroll
                for (int j = 0; j < 4; ++j) a[j] += bv;
            }
            if (CMODE == CM_F32) {
                float* C = (float*)C1 + (long)z * sCz;
#pragma unroll
                for (int j = 0; j < 4; ++j)
                    C[(long)(rbase + j) * ldc + col] = a[j];
            } else if (CMODE == CM_SPLIT) {
                __bf16* Ch = (__bf16*)C1;
                __bf16* Cl = (__bf16*)C2;
#pragma unroll
                for (int j = 0; j < 4; ++j) {
                    const float q = a[j];
                    const __bf16 h = (__bf16)q;
                    Ch[(long)(rbase + j) * ldc + col] = h;
                    Cl[(long)(rbase + j) * ldc + col] = (__bf16)(q - (float)h);
                }
            } else {  // CM_TRANSV: Vt[b][col][s] bf16
                const int b_ = rbase >> 11;
                const int s_ = rbase & (S - 1);
                bf16x4 h;
#pragma unroll
                for (int j = 0; j < 4; ++j) h[j] = (__bf16)a[j];
                *(bf16x4*)((__bf16*)C1 + ((long)b_ * D + col) * S + s_) = h;
            }
        }
    }
}

// ---------------------------------------------------------------------------
__global__ __launch_bounds__(256) void xsplit(
    const float* __restrict__ X, __bf16* __restrict__ Xh, __bf16* __restrict__ Xl)
{
    const long i = ((long)blockIdx.x * 256 + threadIdx.x) * 4;
    f32x4 v = *(const f32x4*)(X + i);
    bf16x4 h, l;
#pragma unroll
    for (int j = 0; j < 4; ++j) {
        h[j] = (__bf16)v[j];
        l[j] = (__bf16)(v[j] - (float)h[j]);
    }
    *(bf16x4*)(Xh + i) = h;
    *(bf16x4*)(Xl + i) = l;
}

// ---------------------------------------------------------------------------
__global__ void wsplit(const float* __restrict__ W0, const float* __restrict__ W1,
                       const float* __restrict__ W2,
                       __bf16* __restrict__ Th, __bf16* __restrict__ Tl)
{
    const float* W = blockIdx.z == 0 ? W0 : (blockIdx.z == 1 ? W1 : W2);
    __bf16* th = Th + (long)blockIdx.z * 1024 * 1024;
    __bf16* tl = Tl + (long)blockIdx.z * 1024 * 1024;
    __shared__ float tile[32][33];
    const int bx = blockIdx.x * 32, by = blockIdx.y * 32;
    const int tx = threadIdx.x, ty = threadIdx.y;
#pragma unroll
    for (int i = ty; i < 32; i += 8) tile[i][tx] = W[(long)(by + i) * 1024 + bx + tx];
    __syncthreads();
#pragma unroll
    for (int i = ty; i < 32; i += 8) {
        const float v = tile[tx][i];
        const __bf16 h = (__bf16)v;
        th[(long)(bx + i) * 1024 + by + tx] = h;
        tl[(long)(bx + i) * 1024 + by + tx] = (__bf16)(v - (float)h);
    }
}

// ---------------------------------------------------------------------------
// Fused row softmax: read f32 score row, write P = exp(s-m)/l as bf16
// IN-PLACE into the start of the row's f32 storage.
// ---------------------------------------------------------------------------
__global__ __launch_bounds__(256) void pconv(float* __restrict__ Sb)
{
    const long row = blockIdx.x;
    float* p = Sb + row * (long)S;
    const int t = threadIdx.x;

    f32x4 x0 = *(const f32x4*)(p + t * 8);
    f32x4 x1 = *(const f32x4*)(p + t * 8 + 4);

    float m = -3.4e38f;
#pragma unroll
    for (int j = 0; j < 4; ++j) m = fmaxf(m, fmaxf(x0[j], x1[j]));
#pragma unroll
    for (int o = 32; o >= 1; o >>= 1) m = fmaxf(m, __shfl_xor(m, o));

    __shared__ float wm[4], wsum[4];
    const int wid = t >> 6, lane = t & 63;
    if (lane == 0) wm[wid] = m;
    __syncthreads();
    m = fmaxf(fmaxf(wm[0], wm[1]), fmaxf(wm[2], wm[3]));

    float e[8], ssum = 0.f;
#pragma unroll
    for (int j = 0; j < 4; ++j) {
        e[j]     = exp2f((x0[j] - m) * LOG2E);
        e[4 + j] = exp2f((x1[j] - m) * LOG2E);
        ssum += e[j] + e[4 + j];
    }
#pragma unroll
    for (int o = 32; o >= 1; o >>= 1) ssum += __shfl_xor(ssum, o);
    if (lane == 0) wsum[wid] = ssum;
    __syncthreads();
    const float invl = 1.0f / (wsum[0] + wsum[1] + wsum[2] + wsum[3]);

    bf16x8 outv;
#pragma unroll
    for (int j = 0; j < 8; ++j) outv[j] = (__bf16)(e[j] * invl);
    *(bf16x8*)((__bf16*)p + t * 8) = outv;
}

// ---------------------------------------------------------------------------
extern "C" void kernel_launch(void* const* d_in, const int* in_sizes, int n_in,
                              void* d_out, int out_size, void* d_ws, size_t ws_size,
                              hipStream_t stream)
{
    const float* X  = (const float*)d_in[0];
    const float* Wq = (const float*)d_in[1];
    const float* bq = (const float*)d_in[2];
    const float* Wk = (const float*)d_in[3];
    const float* bk = (const float*)d_in[4];
    const float* Wv = (const float*)d_in[5];
    const float* bv = (const float*)d_in[6];
    float* out = (float*)d_out;
    char* ws = (char*)d_ws;
    const size_t MB = 1u << 20;

    const bool big = ws_size >= 300 * MB;   // G=8: one full-machine PV dispatch
    const int G = big ? 8 : 4;

    __bf16 *Wth, *Wtl, *Xh, *Xl, *Qh, *Ql, *Kh, *Kl, *Vt;
    float* Sb;
    if (big) {
        // [0,6) Wth  [6,12) Wtl  [12,44) Qh [44,76) Ql [76,108) Kh [108,140) Kl
        // [140,172) Vt  [172,300) Sb f32 [8][S][S]  (Xh/Xl alias Sb's first 64MB)
        Wth = (__bf16*)ws;          Wtl = (__bf16*)(ws + 6 * MB);
        Qh = (__bf16*)(ws + 12 * MB);  Ql = (__bf16*)(ws + 44 * MB);
        Kh = (__bf16*)(ws + 76 * MB);  Kl = (__bf16*)(ws + 108 * MB);
        Vt = (__bf16*)(ws + 140 * MB);
        Sb = (float*)(ws + 172 * MB);
        Xh = (__bf16*)Sb;  Xl = (__bf16*)(ws + 204 * MB);
    } else {
        // round-4 layout (236 MB), G=4
        Wth = (__bf16*)ws;          Wtl = (__bf16*)(ws + 6 * MB);
        Xh = (__bf16*)(ws + 12 * MB);  Xl = (__bf16*)(ws + 44 * MB);
        Qh = (__bf16*)(ws + 76 * MB);  Ql = (__bf16*)(ws + 108 * MB);
        Kh = (__bf16*)(ws + 140 * MB); Kl = (__bf16*)(ws + 172 * MB);
        Vt = (__bf16*)(ws + 204 * MB);
        Sb = (float*)(ws + 12 * MB);
    }

    const int DYN_LDS = 131072;
    hipFuncSetAttribute(reinterpret_cast<const void*>(&bgemm256<3, CM_SPLIT>),
                        hipFuncAttributeMaxDynamicSharedMemorySize, DYN_LDS);
    hipFuncSetAttribute(reinterpret_cast<const void*>(&bgemm256<3, CM_TRANSV>),
                        hipFuncAttributeMaxDynamicSharedMemorySize, DYN_LDS);
    hipFuncSetAttribute(reinterpret_cast<const void*>(&bgemm256<3, CM_F32>),
                        hipFuncAttributeMaxDynamicSharedMemorySize, DYN_LDS);
    hipFuncSetAttribute(reinterpret_cast<const void*>(&bgemm256<1, CM_F32>),
                        hipFuncAttributeMaxDynamicSharedMemorySize, DYN_LDS);

    // 1) split inputs to bf16 hi/lo planes
    xsplit<<<dim3(16384), 256, 0, stream>>>(X, Xh, Xl);
    wsplit<<<dim3(32, 32, 3), dim3(32, 8), 0, stream>>>(Wq, Wk, Wv, Wth, Wtl);

    // 2) projections (3-term split GEMM)
    const long MW = 1024 * 1024;
    bgemm256<3, CM_SPLIT><<<dim3(D / 256, 16384 / 256, 1), 512, DYN_LDS, stream>>>(
        Xh, Xl, 0, Wth, Wtl, 0, D, D, Qh, Ql, D, 0, bq, D);
    bgemm256<3, CM_SPLIT><<<dim3(D / 256, 16384 / 256, 1), 512, DYN_LDS, stream>>>(
        Xh, Xl, 0, Wth + MW, Wtl + MW, 0, D, D, Kh, Kl, D, 0, bk, D);
    bgemm256<3, CM_TRANSV><<<dim3(D / 256, 16384 / 256, 1), 512, DYN_LDS, stream>>>(
        Xh, Xl, 0, Wth + 2 * MW, Wtl + 2 * MW, 0, D, D, Vt, nullptr, 0, 0, bv, D);

    // 3) per G-batch group: scores -> in-place softmax->bf16 P -> PV
    for (int b0 = 0; b0 < NB; b0 += G) {
        bgemm256<3, CM_F32><<<dim3(S / 256, S / 256, G), 512, DYN_LDS, stream>>>(
            Qh + (long)b0 * S * D, Ql + (long)b0 * S * D, (long)S * D,
            Kh + (long)b0 * S * D, Kl + (long)b0 * S * D, (long)S * D,
            D, D, Sb, nullptr, S, (long)S * S, nullptr, D);
        pconv<<<dim3(G * S), 256, 0, stream>>>(Sb);
        // PV: A = bf16 P rows embedded in f32 buffer (lda = 2S bf16 elements)
        bgemm256<1, CM_F32><<<dim3(D / 256, S / 256, G), 512, DYN_LDS, stream>>>(
            (const __bf16*)Sb, nullptr, 2L * S * S,
            Vt + (long)b0 * D * S, nullptr, (long)D * S,
            2 * S, S, out + (long)b0 * S * D, nullptr, D, (long)S * D, nullptr, S);
    }
}

// Round 6
// 624.756 us; speedup vs baseline: 1.8849x; 1.0409x over previous
//
#include <hip/hip_runtime.h>
#include <hip/hip_bf16.h>

// B=8, S=2048, D=1024, fp32 in/out.
static constexpr int S = 2048;
static constexpr int D = 1024;
static constexpr int NB = 8;

#define LOG2E 1.4426950408889634f

typedef float  f32x4  __attribute__((ext_vector_type(4)));
typedef __bf16 bf16x4 __attribute__((ext_vector_type(4)));
typedef __bf16 bf16x8 __attribute__((ext_vector_type(8)));

#define CM_F32    0
#define CM_SPLIT  1
#define CM_TRANSV 2

#define GLD16(g, l) __builtin_amdgcn_global_load_lds(                         \
    (const __attribute__((address_space(1))) void*)(g),                       \
    (__attribute__((address_space(3))) void*)(l), 16, 0, 0)

#define MFMA16(a, b, c) __builtin_amdgcn_mfma_f32_16x16x32_bf16((a), (b), (c), 0, 0, 0)

// ---------------------------------------------------------------------------
// 256xBNT tile, 8 waves, pipelined K-loop with counted vmcnt (lead >= 2 phases).
//   TERMS==3: K-tile = 32 real k; chunks 0-3 = hi plane, 4-7 = lo plane.
//             acc += Ah*Bh + Ah*Bl + Al*Bh  (split-bf16 fp32 emulation), 4 phases
//   TERMS==1: K-tile = 64 k; chunks 0-7 = k 0..63. acc += A*B, 2 phases
// LDS: A = 2 bufs x 32 KB at 0; B = 2 bufs x (BNT*128 B) at 64 KB.
// Swizzle (both sides, round-5-verified 0-conflict): LDS slot s of row r holds
// global chunk s^(r&7); stage reads global chunk (lane&7)^(lane>>3), LDS linear.
// Stage units (2 gload_lds each): A-half0, A-half1, B-half0 issued at ph0 of
// the PREVIOUS tile's compute, B-half1 (BNT=256 only) at ph1 -> every unit has
// >=3-phase lead. Wait vmcnt(6) at ph0 (retires exactly the current tile's
// loads, leaves the 6 just-issued), vmcnt(0) on the last tile. Raw s_barrier.
// ---------------------------------------------------------------------------
template <int TERMS, int CMODE, int BNT>
__global__ __launch_bounds__(512, 1) void bgemm256(
    const __bf16* __restrict__ Ah_, const __bf16* __restrict__ Al_, long sAz,
    const __bf16* __restrict__ Bh_, const __bf16* __restrict__ Bl_, long sBz,
    int lda, int ldb,
    void* __restrict__ C1, void* __restrict__ C2, int ldc, long sCz,
    const float* __restrict__ bias, int K)
{
    extern __shared__ char smem[];
    constexpr int NW_N = BNT / 64;        // waves along N
    constexpr int NW_M = 8 / NW_N;        // waves along M
    constexpr int WM   = 256 / NW_M;      // rows per wave tile
    constexpr int MI   = WM / 16;         // acc rows per wave
    constexpr int MH   = MI / 2;
    constexpr int BBUF = BNT * 128;       // bytes per B buffer

    const int t = threadIdx.x;
    const int z = blockIdx.z;
    const int m0 = blockIdx.y * 256;
    const int n0 = blockIdx.x * BNT;
    const int lane = t & 63, wid = t >> 6;
    const int wr = wid / NW_N, wc = wid % NW_N;
    const int fr = lane & 15, fq = lane >> 4;
    const int srow = lane >> 3;                 // 0..7
    const int schunk = (lane & 7) ^ srow;       // swizzled global chunk 0..7
    const int rowbase = wid * 8 + srow;

    const __bf16* Ahz = Ah_ + (long)z * sAz;
    const __bf16* Alz = (TERMS == 3) ? Al_ + (long)z * sAz : nullptr;
    const __bf16* Bhz = Bh_ + (long)z * sBz;
    const __bf16* Blz = (TERMS == 3) ? Bl_ + (long)z * sBz : nullptr;

    auto stA = [&](int tile, int h) {
        const long kk = (TERMS == 3) ? (long)tile * 32 + (schunk & 3) * 8
                                     : (long)tile * 64 + schunk * 8;
        const __bf16* plane = (TERMS == 3 && schunk >= 4) ? Alz : Ahz;
        char* lbase = smem + (tile & 1) * 32768 + (h * 128 + wid * 8) * 128;
#pragma unroll
        for (int i = 0; i < 2; ++i)
            GLD16(plane + (long)(m0 + h * 128 + i * 64 + rowbase) * lda + kk,
                  lbase + i * 8192);
    };
    auto stB = [&](int tile, int h) {
        const long kk = (TERMS == 3) ? (long)tile * 32 + (schunk & 3) * 8
                                     : (long)tile * 64 + schunk * 8;
        const __bf16* plane = (TERMS == 3 && schunk >= 4) ? Blz : Bhz;
        char* lbase = smem + 65536 + (tile & 1) * BBUF + (h * 128 + wid * 8) * 128;
#pragma unroll
        for (int i = 0; i < 2; ++i)
            GLD16(plane + (long)(n0 + h * 128 + i * 64 + rowbase) * ldb + kk,
                  lbase + i * 8192);
    };
    auto rdA = [&](int buf, int c, int mi) -> bf16x8 {
        const int row = wr * WM + mi * 16 + fr;
        return *(const bf16x8*)(smem + buf * 32768 + row * 128 +
                                ((c ^ (row & 7)) << 4));
    };
    auto rdB = [&](int buf, int c, int ni) -> bf16x8 {
        const int row = wc * 64 + ni * 16 + fr;
        return *(const bf16x8*)(smem + 65536 + buf * BBUF + row * 128 +
                                ((c ^ (row & 7)) << 4));
    };

    f32x4 acc[MI][4] = {};
    const int ktiles = K / ((TERMS == 3) ? 32 : 64);

    // prologue: stage tile 0 (same unit order as in-loop issue order)
    stA(0, 0); stA(0, 1); stB(0, 0);
    if (BNT == 256) stB(0, 1);

    for (int tt = 0; tt < ktiles; ++tt) {
        const int buf = tt & 1;
        const bool pf = (tt + 1 < ktiles);
        bf16x8 b0[4], b1[4], a[MH], ah[MH];

        // ---------------- phase 0: slot0 (chunk fq), mi 0..MH-1 ----------------
        if (pf) {
            stA(tt + 1, 0); stA(tt + 1, 1); stB(tt + 1, 0);
            asm volatile("s_waitcnt vmcnt(6)" ::: "memory");
        } else {
            asm volatile("s_waitcnt vmcnt(0)" ::: "memory");
        }
        __builtin_amdgcn_s_barrier();
#pragma unroll
        for (int ni = 0; ni < 4; ++ni) b0[ni] = rdB(buf, fq, ni);
#pragma unroll
        for (int mi = 0; mi < MH; ++mi) a[mi] = rdA(buf, fq, mi);
        __builtin_amdgcn_s_setprio(1);
#pragma unroll
        for (int mi = 0; mi < MH; ++mi)
#pragma unroll
            for (int ni = 0; ni < 4; ++ni)
                acc[mi][ni] = MFMA16(a[mi], b0[ni], acc[mi][ni]);
        __builtin_amdgcn_s_setprio(0);
        __builtin_amdgcn_s_barrier();

        // ---------------- phase 1: slot0, mi MH..MI-1 ----------------
        if (BNT == 256 && pf) stB(tt + 1, 1);
#pragma unroll
        for (int mi = 0; mi < MH; ++mi) a[mi] = rdA(buf, fq, MH + mi);
        __builtin_amdgcn_s_setprio(1);
#pragma unroll
        for (int mi = 0; mi < MH; ++mi)
#pragma unroll
            for (int ni = 0; ni < 4; ++ni)
                acc[MH + mi][ni] = MFMA16(a[mi], b0[ni], acc[MH + mi][ni]);
        __builtin_amdgcn_s_setprio(0);
        __builtin_amdgcn_s_barrier();

        // ---------------- phase 2: slot1 (chunk 4+fq), mi 0..MH-1 ----------------
#pragma unroll
        for (int ni = 0; ni < 4; ++ni) b1[ni] = rdB(buf, 4 + fq, ni);
#pragma unroll
        for (int mi = 0; mi < MH; ++mi) a[mi] = rdA(buf, 4 + fq, mi);
        if (TERMS == 3) {
#pragma unroll
            for (int mi = 0; mi < MH; ++mi) ah[mi] = rdA(buf, fq, mi);
        }
        __builtin_amdgcn_s_setprio(1);
#pragma unroll
        for (int mi = 0; mi < MH; ++mi)
#pragma unroll
            for (int ni = 0; ni < 4; ++ni) {
                if (TERMS == 3) {
                    acc[mi][ni] = MFMA16(ah[mi], b1[ni], acc[mi][ni]);  // hi*lo
                    acc[mi][ni] = MFMA16(a[mi], b0[ni], acc[mi][ni]);   // lo*hi
                } else {
                    acc[mi][ni] = MFMA16(a[mi], b1[ni], acc[mi][ni]);   // k-half 1
                }
            }
        __builtin_amdgcn_s_setprio(0);
        __builtin_amdgcn_s_barrier();

        // ---------------- phase 3: slot1, mi MH..MI-1 ----------------
#pragma unroll
        for (int mi = 0; mi < MH; ++mi) a[mi] = rdA(buf, 4 + fq, MH + mi);
        if (TERMS == 3) {
#pragma unroll
            for (int mi = 0; mi < MH; ++mi) ah[mi] = rdA(buf, fq, MH + mi);
        }
        __builtin_amdgcn_s_setprio(1);
#pragma unroll
        for (int mi = 0; mi < MH; ++mi)
#pragma unroll
            for (int ni = 0; ni < 4; ++ni) {
                if (TERMS == 3) {
                    acc[MH + mi][ni] = MFMA16(ah[mi], b1[ni], acc[MH + mi][ni]);
                    acc[MH + mi][ni] = MFMA16(a[mi], b0[ni], acc[MH + mi][ni]);
                } else {
                    acc[MH + mi][ni] = MFMA16(a[mi], b1[ni], acc[MH + mi][ni]);
                }
            }
        __builtin_amdgcn_s_setprio(0);
        __builtin_amdgcn_s_barrier();
    }

    // ---------------- epilogue ----------------
#pragma unroll
    for (int mi = 0; mi < MI; ++mi) {
        const int rbase = m0 + wr * WM + mi * 16 + fq * 4;
#pragma unroll
        for (int ni = 0; ni < 4; ++ni) {
            const int col = n0 + wc * 64 + ni * 16 + fr;
            f32x4 a = acc[mi][ni];
            if (CMODE != CM_F32) {
                const float bv = bias[col];
#pragma unroll
                for (int j = 0; j < 4; ++j) a[j] += bv;
            }
            if (CMODE == CM_F32) {
                float* C = (float*)C1 + (long)z * sCz;
#pragma unroll
                for (int j = 0; j < 4; ++j)
                    C[(long)(rbase + j) * ldc + col] = a[j];
            } else if (CMODE == CM_SPLIT) {
                __bf16* Ch = (__bf16*)C1;
                __bf16* Cl = (__bf16*)C2;
#pragma unroll
                for (int j = 0; j < 4; ++j) {
                    const float q = a[j];
                    const __bf16 h = (__bf16)q;
                    Ch[(long)(rbase + j) * ldc + col] = h;
                    Cl[(long)(rbase + j) * ldc + col] = (__bf16)(q - (float)h);
                }
            } else {  // CM_TRANSV: Vt[b][col][s] bf16
                const int b_ = rbase >> 11;
                const int s_ = rbase & (S - 1);
                bf16x4 h;
#pragma unroll
                for (int j = 0; j < 4; ++j) h[j] = (__bf16)a[j];
                *(bf16x4*)((__bf16*)C1 + ((long)b_ * D + col) * S + s_) = h;
            }
        }
    }
}

// ---------------------------------------------------------------------------
__global__ __launch_bounds__(256) void xsplit(
    const float* __restrict__ X, __bf16* __restrict__ Xh, __bf16* __restrict__ Xl)
{
    const long i = ((long)blockIdx.x * 256 + threadIdx.x) * 4;
    f32x4 v = *(const f32x4*)(X + i);
    bf16x4 h, l;
#pragma unroll
    for (int j = 0; j < 4; ++j) {
        h[j] = (__bf16)v[j];
        l[j] = (__bf16)(v[j] - (float)h[j]);
    }
    *(bf16x4*)(Xh + i) = h;
    *(bf16x4*)(Xl + i) = l;
}

// ---------------------------------------------------------------------------
__global__ void wsplit(const float* __restrict__ W0, const float* __restrict__ W1,
                       const float* __restrict__ W2,
                       __bf16* __restrict__ Th, __bf16* __restrict__ Tl)
{
    const float* W = blockIdx.z == 0 ? W0 : (blockIdx.z == 1 ? W1 : W2);
    __bf16* th = Th + (long)blockIdx.z * 1024 * 1024;
    __bf16* tl = Tl + (long)blockIdx.z * 1024 * 1024;
    __shared__ float tile[32][33];
    const int bx = blockIdx.x * 32, by = blockIdx.y * 32;
    const int tx = threadIdx.x, ty = threadIdx.y;
#pragma unroll
    for (int i = ty; i < 32; i += 8) tile[i][tx] = W[(long)(by + i) * 1024 + bx + tx];
    __syncthreads();
#pragma unroll
    for (int i = ty; i < 32; i += 8) {
        const float v = tile[tx][i];
        const __bf16 h = (__bf16)v;
        th[(long)(bx + i) * 1024 + by + tx] = h;
        tl[(long)(bx + i) * 1024 + by + tx] = (__bf16)(v - (float)h);
    }
}

// ---------------------------------------------------------------------------
// Fused row softmax: read f32 score row, write P = exp(s-m)/l as bf16
// IN-PLACE into the start of the row's f32 storage.
// ---------------------------------------------------------------------------
__global__ __launch_bounds__(256) void pconv(float* __restrict__ Sb)
{
    const long row = blockIdx.x;
    float* p = Sb + row * (long)S;
    const int t = threadIdx.x;

    f32x4 x0 = *(const f32x4*)(p + t * 8);
    f32x4 x1 = *(const f32x4*)(p + t * 8 + 4);

    float m = -3.4e38f;
#pragma unroll
    for (int j = 0; j < 4; ++j) m = fmaxf(m, fmaxf(x0[j], x1[j]));
#pragma unroll
    for (int o = 32; o >= 1; o >>= 1) m = fmaxf(m, __shfl_xor(m, o));

    __shared__ float wm[4], wsum[4];
    const int wid = t >> 6, lane = t & 63;
    if (lane == 0) wm[wid] = m;
    __syncthreads();
    m = fmaxf(fmaxf(wm[0], wm[1]), fmaxf(wm[2], wm[3]));

    float e[8], ssum = 0.f;
#pragma unroll
    for (int j = 0; j < 4; ++j) {
        e[j]     = exp2f((x0[j] - m) * LOG2E);
        e[4 + j] = exp2f((x1[j] - m) * LOG2E);
        ssum += e[j] + e[4 + j];
    }
#pragma unroll
    for (int o = 32; o >= 1; o >>= 1) ssum += __shfl_xor(ssum, o);
    if (lane == 0) wsum[wid] = ssum;
    __syncthreads();
    const float invl = 1.0f / (wsum[0] + wsum[1] + wsum[2] + wsum[3]);

    bf16x8 outv;
#pragma unroll
    for (int j = 0; j < 8; ++j) outv[j] = (__bf16)(e[j] * invl);
    *(bf16x8*)((__bf16*)p + t * 8) = outv;
}

// ---------------------------------------------------------------------------
extern "C" void kernel_launch(void* const* d_in, const int* in_sizes, int n_in,
                              void* d_out, int out_size, void* d_ws, size_t ws_size,
                              hipStream_t stream)
{
    const float* X  = (const float*)d_in[0];
    const float* Wq = (const float*)d_in[1];
    const float* bq = (const float*)d_in[2];
    const float* Wk = (const float*)d_in[3];
    const float* bk = (const float*)d_in[4];
    const float* Wv = (const float*)d_in[5];
    const float* bv = (const float*)d_in[6];
    float* out = (float*)d_out;
    char* ws = (char*)d_ws;
    const size_t MB = 1u << 20;

    // layout (236 MB):
    // [0,6) Wth[3]  [6,12) Wtl[3]
    // [12,76) X region: Xh|Xl during projections; Sb f32 [4][S][S] after (P in-place)
    // [76,108) Qh  [108,140) Ql  [140,172) Kh  [172,204) Kl  [204,236) Vt bf16
    __bf16* Wth = (__bf16*)ws;          __bf16* Wtl = (__bf16*)(ws + 6 * MB);
    __bf16* Xh = (__bf16*)(ws + 12 * MB);  __bf16* Xl = (__bf16*)(ws + 44 * MB);
    __bf16* Qh = (__bf16*)(ws + 76 * MB);  __bf16* Ql = (__bf16*)(ws + 108 * MB);
    __bf16* Kh = (__bf16*)(ws + 140 * MB); __bf16* Kl = (__bf16*)(ws + 172 * MB);
    __bf16* Vt = (__bf16*)(ws + 204 * MB);
    float*  Sb = (float*)(ws + 12 * MB);   // [4][S][S] f32; P bf16 in-place

    const int LDS_T3 = 131072;             // 64K A + 2x32K B
    const int LDS_T1 = 98304;              // 64K A + 2x16K B
    hipFuncSetAttribute(reinterpret_cast<const void*>(&bgemm256<3, CM_SPLIT, 256>),
                        hipFuncAttributeMaxDynamicSharedMemorySize, LDS_T3);
    hipFuncSetAttribute(reinterpret_cast<const void*>(&bgemm256<3, CM_TRANSV, 256>),
                        hipFuncAttributeMaxDynamicSharedMemorySize, LDS_T3);
    hipFuncSetAttribute(reinterpret_cast<const void*>(&bgemm256<3, CM_F32, 256>),
                        hipFuncAttributeMaxDynamicSharedMemorySize, LDS_T3);
    hipFuncSetAttribute(reinterpret_cast<const void*>(&bgemm256<1, CM_F32, 128>),
                        hipFuncAttributeMaxDynamicSharedMemorySize, LDS_T1);

    // 1) split inputs to bf16 hi/lo planes
    xsplit<<<dim3(16384), 256, 0, stream>>>(X, Xh, Xl);
    wsplit<<<dim3(32, 32, 3), dim3(32, 8), 0, stream>>>(Wq, Wk, Wv, Wth, Wtl);

    // 2) projections (3-term split GEMM)
    const long MW = 1024 * 1024;
    bgemm256<3, CM_SPLIT, 256><<<dim3(D / 256, 64, 1), 512, LDS_T3, stream>>>(
        Xh, Xl, 0, Wth, Wtl, 0, D, D, Qh, Ql, D, 0, bq, D);
    bgemm256<3, CM_SPLIT, 256><<<dim3(D / 256, 64, 1), 512, LDS_T3, stream>>>(
        Xh, Xl, 0, Wth + MW, Wtl + MW, 0, D, D, Kh, Kl, D, 0, bk, D);
    bgemm256<3, CM_TRANSV, 256><<<dim3(D / 256, 64, 1), 512, LDS_T3, stream>>>(
        Xh, Xl, 0, Wth + 2 * MW, Wtl + 2 * MW, 0, D, D, Vt, nullptr, 0, 0, bv, D);

    // 3) per 4-batch group: scores -> in-place softmax->bf16 P -> PV
    for (int g = 0; g < 2; ++g) {
        const int b0 = g * 4;
        bgemm256<3, CM_F32, 256><<<dim3(S / 256, S / 256, 4), 512, LDS_T3, stream>>>(
            Qh + (long)b0 * S * D, Ql + (long)b0 * S * D, (long)S * D,
            Kh + (long)b0 * S * D, Kl + (long)b0 * S * D, (long)S * D,
            D, D, Sb, nullptr, S, (long)S * S, nullptr, D);
        pconv<<<dim3(4 * S), 256, 0, stream>>>(Sb);
        // PV: A = bf16 P rows embedded in f32 buffer (lda = 2S bf16 elements)
        bgemm256<1, CM_F32, 128><<<dim3(D / 128, S / 256, 4), 512, LDS_T1, stream>>>(
            (const __bf16*)Sb, nullptr, 2L * S * S,
            Vt + (long)b0 * D * S, nullptr, (long)D * S,
            2 * S, S, out + (long)b0 * S * D, nullptr, D, (long)S * D, nullptr, S);
    }
}

// Round 7
// 617.973 us; speedup vs baseline: 1.9056x; 1.0110x over previous
//
#include <hip/hip_runtime.h>
#include <hip/hip_bf16.h>

// B=8, S=2048, D=1024, fp32 in/out.
static constexpr int S = 2048;
static constexpr int D = 1024;
static constexpr int NB = 8;

#define LOG2E 1.4426950408889634f

typedef float  f32x4  __attribute__((ext_vector_type(4)));
typedef __bf16 bf16x4 __attribute__((ext_vector_type(4)));
typedef __bf16 bf16x8 __attribute__((ext_vector_type(8)));

#define CM_F32    0
#define CM_SPLIT  1
#define CM_TRANSV 2

#define GLD16(g, l) __builtin_amdgcn_global_load_lds(                         \
    (const __attribute__((address_space(1))) void*)(g),                       \
    (__attribute__((address_space(3))) void*)(l), 16, 0, 0)

#define MFMA16(a, b, c) __builtin_amdgcn_mfma_f32_16x16x32_bf16((a), (b), (c), 0, 0, 0)

// ---------------------------------------------------------------------------
// 256xBNT tile, 8 waves, 2-phase/tile pipelined K-loop, counted vmcnt,
// 2 barriers per K-tile.
//   TERMS==3: K-tile = 32 real k; chunks 0-3 = hi plane, 4-7 = lo plane.
//             ph0: acc += Ah*Bh (a0 kept in regs); ph1: acc += Ah*Bl + Al*Bh.
//   TERMS==1: K-tile = 64 k; chunks 0-7 = k 0..63.
//             ph0: acc += A(k0-31)*B(k0-31); ph1: acc += A(k32-63)*B(k32-63).
// LDS: A = 2 bufs x 32 KB at 0; B = 2 bufs x (BNT*128 B) at 64 KB.
// Swizzle (both sides, 0-conflict verified r5): LDS slot s of row r holds
// global chunk s^(r&7); stage reads global chunk (lane&7)^(lane>>3), LDS linear.
// All stage units for tile t+1 issue at t.ph0 (after the end-of-(t-1) barrier,
// so buf^1 is quiescent). Wait vmcnt(#inflight-prefetch) at ph0; vmcnt(0) only
// on the last tile. End-of-tile: lgkmcnt(0)+sched_barrier+s_barrier (raw
// s_barrier does not drain lgkm; reads of buf must land before t+1 restages).
// ---------------------------------------------------------------------------
template <int TERMS, int CMODE, int BNT>
__global__ __launch_bounds__(512, 1) void bgemm256(
    const __bf16* __restrict__ Ah_, const __bf16* __restrict__ Al_, long sAz,
    const __bf16* __restrict__ Bh_, const __bf16* __restrict__ Bl_, long sBz,
    int lda, int ldb,
    void* __restrict__ C1, void* __restrict__ C2, int ldc, long sCz,
    const float* __restrict__ bias, int K)
{
    extern __shared__ char smem[];
    constexpr int NW_N = BNT / 64;        // waves along N
    constexpr int NW_M = 8 / NW_N;        // waves along M
    constexpr int WM   = 256 / NW_M;      // rows per wave tile
    constexpr int MI   = WM / 16;         // acc rows per wave
    constexpr int BBUF = BNT * 128;       // bytes per B buffer
    constexpr int BH   = BNT / 128;       // B stage halves (1 or 2)

    const int t = threadIdx.x;
    const int z = blockIdx.z;
    const int m0 = blockIdx.y * 256;
    const int n0 = blockIdx.x * BNT;
    const int lane = t & 63, wid = t >> 6;
    const int wr = wid / NW_N, wc = wid % NW_N;
    const int fr = lane & 15, fq = lane >> 4;
    const int srow = lane >> 3;                 // 0..7
    const int schunk = (lane & 7) ^ srow;       // swizzled global chunk 0..7
    const int rowbase = wid * 8 + srow;

    const __bf16* Ahz = Ah_ + (long)z * sAz;
    const __bf16* Alz = (TERMS == 3) ? Al_ + (long)z * sAz : nullptr;
    const __bf16* Bhz = Bh_ + (long)z * sBz;
    const __bf16* Blz = (TERMS == 3) ? Bl_ + (long)z * sBz : nullptr;

    auto stA = [&](int tile, int h) {
        const long kk = (TERMS == 3) ? (long)tile * 32 + (schunk & 3) * 8
                                     : (long)tile * 64 + schunk * 8;
        const __bf16* plane = (TERMS == 3 && schunk >= 4) ? Alz : Ahz;
        char* lbase = smem + (tile & 1) * 32768 + (h * 128 + wid * 8) * 128;
#pragma unroll
        for (int i = 0; i < 2; ++i)
            GLD16(plane + (long)(m0 + h * 128 + i * 64 + rowbase) * lda + kk,
                  lbase + i * 8192);
    };
    auto stB = [&](int tile, int h) {
        const long kk = (TERMS == 3) ? (long)tile * 32 + (schunk & 3) * 8
                                     : (long)tile * 64 + schunk * 8;
        const __bf16* plane = (TERMS == 3 && schunk >= 4) ? Blz : Bhz;
        char* lbase = smem + 65536 + (tile & 1) * BBUF + (h * 128 + wid * 8) * 128;
#pragma unroll
        for (int i = 0; i < 2; ++i)
            GLD16(plane + (long)(n0 + h * 128 + i * 64 + rowbase) * ldb + kk,
                  lbase + i * 8192);
    };
    auto rdA = [&](int buf, int c, int mi) -> bf16x8 {
        const int row = wr * WM + mi * 16 + fr;
        return *(const bf16x8*)(smem + buf * 32768 + row * 128 +
                                ((c ^ (row & 7)) << 4));
    };
    auto rdB = [&](int buf, int c, int ni) -> bf16x8 {
        const int row = wc * 64 + ni * 16 + fr;
        return *(const bf16x8*)(smem + 65536 + buf * BBUF + row * 128 +
                                ((c ^ (row & 7)) << 4));
    };

    f32x4 acc[MI][4] = {};
    const int ktiles = K / ((TERMS == 3) ? 32 : 64);

    // prologue: stage tile 0 (same unit order as in-loop issue order)
    stA(0, 0); stA(0, 1); stB(0, 0);
    if (BH == 2) stB(0, 1);

    for (int tt = 0; tt < ktiles; ++tt) {
        const int buf = tt & 1;
        const bool pf = (tt + 1 < ktiles);
        bf16x8 a0[MI], b0[4], b1[4];

        // ---------------- phase 0: slot0 (chunk fq), all mi ----------------
        if (pf) {
            stA(tt + 1, 0); stA(tt + 1, 1); stB(tt + 1, 0);
            if (BH == 2) stB(tt + 1, 1);
            if (BH == 2) asm volatile("s_waitcnt vmcnt(8)" ::: "memory");
            else         asm volatile("s_waitcnt vmcnt(6)" ::: "memory");
        } else {
            asm volatile("s_waitcnt vmcnt(0)" ::: "memory");
        }
        __builtin_amdgcn_s_barrier();
#pragma unroll
        for (int ni = 0; ni < 4; ++ni) b0[ni] = rdB(buf, fq, ni);
#pragma unroll
        for (int mi = 0; mi < MI; ++mi) a0[mi] = rdA(buf, fq, mi);
        __builtin_amdgcn_s_setprio(1);
#pragma unroll
        for (int mi = 0; mi < MI; ++mi)
#pragma unroll
            for (int ni = 0; ni < 4; ++ni)
                acc[mi][ni] = MFMA16(a0[mi], b0[ni], acc[mi][ni]);
        __builtin_amdgcn_s_setprio(0);

        // ---------------- phase 1: slot1 (chunk 4+fq), all mi ----------------
        // (no barrier needed: same buf, staged before tile start)
#pragma unroll
        for (int ni = 0; ni < 4; ++ni) b1[ni] = rdB(buf, 4 + fq, ni);
        __builtin_amdgcn_s_setprio(1);
#pragma unroll
        for (int mi = 0; mi < MI; ++mi) {
            const bf16x8 a1 = rdA(buf, 4 + fq, mi);
#pragma unroll
            for (int ni = 0; ni < 4; ++ni) {
                if (TERMS == 3) {
                    acc[mi][ni] = MFMA16(a0[mi], b1[ni], acc[mi][ni]);  // hi*lo
                    acc[mi][ni] = MFMA16(a1, b0[ni], acc[mi][ni]);      // lo*hi
                } else {
                    acc[mi][ni] = MFMA16(a1, b1[ni], acc[mi][ni]);      // k-half 1
                }
            }
        }
        __builtin_amdgcn_s_setprio(0);
        // all reads of buf must have landed before tile t+1 restages it
        asm volatile("s_waitcnt lgkmcnt(0)" ::: "memory");
        __builtin_amdgcn_sched_barrier(0);
        __builtin_amdgcn_s_barrier();
    }

    // ---------------- epilogue ----------------
#pragma unroll
    for (int mi = 0; mi < MI; ++mi) {
        const int rbase = m0 + wr * WM + mi * 16 + fq * 4;
#pragma unroll
        for (int ni = 0; ni < 4; ++ni) {
            const int col = n0 + wc * 64 + ni * 16 + fr;
            f32x4 a = acc[mi][ni];
            if (CMODE != CM_F32) {
                const float bv = bias[col];
#pragma unroll
                for (int j = 0; j < 4; ++j) a[j] += bv;
            }
            if (CMODE == CM_F32) {
                float* C = (float*)C1 + (long)z * sCz;
#pragma unroll
                for (int j = 0; j < 4; ++j)
                    C[(long)(rbase + j) * ldc + col] = a[j];
            } else if (CMODE == CM_SPLIT) {
                __bf16* Ch = (__bf16*)C1;
                __bf16* Cl = (__bf16*)C2;
#pragma unroll
                for (int j = 0; j < 4; ++j) {
                    const float q = a[j];
                    const __bf16 h = (__bf16)q;
                    Ch[(long)(rbase + j) * ldc + col] = h;
                    Cl[(long)(rbase + j) * ldc + col] = (__bf16)(q - (float)h);
                }
            } else {  // CM_TRANSV: Vt[b][col][s] bf16
                const int b_ = rbase >> 11;
                const int s_ = rbase & (S - 1);
                bf16x4 h;
#pragma unroll
                for (int j = 0; j < 4; ++j) h[j] = (__bf16)a[j];
                *(bf16x4*)((__bf16*)C1 + ((long)b_ * D + col) * S + s_) = h;
            }
        }
    }
}

// ---------------------------------------------------------------------------
__global__ __launch_bounds__(256) void xsplit(
    const float* __restrict__ X, __bf16* __restrict__ Xh, __bf16* __restrict__ Xl)
{
    const long i = ((long)blockIdx.x * 256 + threadIdx.x) * 4;
    f32x4 v = *(const f32x4*)(X + i);
    bf16x4 h, l;
#pragma unroll
    for (int j = 0; j < 4; ++j) {
        h[j] = (__bf16)v[j];
        l[j] = (__bf16)(v[j] - (float)h[j]);
    }
    *(bf16x4*)(Xh + i) = h;
    *(bf16x4*)(Xl + i) = l;
}

// ---------------------------------------------------------------------------
__global__ void wsplit(const float* __restrict__ W0, const float* __restrict__ W1,
                       const float* __restrict__ W2,
                       __bf16* __restrict__ Th, __bf16* __restrict__ Tl)
{
    const float* W = blockIdx.z == 0 ? W0 : (blockIdx.z == 1 ? W1 : W2);
    __bf16* th = Th + (long)blockIdx.z * 1024 * 1024;
    __bf16* tl = Tl + (long)blockIdx.z * 1024 * 1024;
    __shared__ float tile[32][33];
    const int bx = blockIdx.x * 32, by = blockIdx.y * 32;
    const int tx = threadIdx.x, ty = threadIdx.y;
#pragma unroll
    for (int i = ty; i < 32; i += 8) tile[i][tx] = W[(long)(by + i) * 1024 + bx + tx];
    __syncthreads();
#pragma unroll
    for (int i = ty; i < 32; i += 8) {
        const float v = tile[tx][i];
        const __bf16 h = (__bf16)v;
        th[(long)(bx + i) * 1024 + by + tx] = h;
        tl[(long)(bx + i) * 1024 + by + tx] = (__bf16)(v - (float)h);
    }
}

// ---------------------------------------------------------------------------
// Fused row softmax: read f32 score row, write P = exp(s-m)/l as bf16
// IN-PLACE into the start of the row's f32 storage.
// ---------------------------------------------------------------------------
__global__ __launch_bounds__(256) void pconv(float* __restrict__ Sb)
{
    const long row = blockIdx.x;
    float* p = Sb + row * (long)S;
    const int t = threadIdx.x;

    f32x4 x0 = *(const f32x4*)(p + t * 8);
    f32x4 x1 = *(const f32x4*)(p + t * 8 + 4);

    float m = -3.4e38f;
#pragma unroll
    for (int j = 0; j < 4; ++j) m = fmaxf(m, fmaxf(x0[j], x1[j]));
#pragma unroll
    for (int o = 32; o >= 1; o >>= 1) m = fmaxf(m, __shfl_xor(m, o));

    __shared__ float wm[4], wsum[4];
    const int wid = t >> 6, lane = t & 63;
    if (lane == 0) wm[wid] = m;
    __syncthreads();
    m = fmaxf(fmaxf(wm[0], wm[1]), fmaxf(wm[2], wm[3]));

    float e[8], ssum = 0.f;
#pragma unroll
    for (int j = 0; j < 4; ++j) {
        e[j]     = exp2f((x0[j] - m) * LOG2E);
        e[4 + j] = exp2f((x1[j] - m) * LOG2E);
        ssum += e[j] + e[4 + j];
    }
#pragma unroll
    for (int o = 32; o >= 1; o >>= 1) ssum += __shfl_xor(ssum, o);
    if (lane == 0) wsum[wid] = ssum;
    __syncthreads();
    const float invl = 1.0f / (wsum[0] + wsum[1] + wsum[2] + wsum[3]);

    bf16x8 outv;
#pragma unroll
    for (int j = 0; j < 8; ++j) outv[j] = (__bf16)(e[j] * invl);
    *(bf16x8*)((__bf16*)p + t * 8) = outv;
}

// ---------------------------------------------------------------------------
extern "C" void kernel_launch(void* const* d_in, const int* in_sizes, int n_in,
                              void* d_out, int out_size, void* d_ws, size_t ws_size,
                              hipStream_t stream)
{
    const float* X  = (const float*)d_in[0];
    const float* Wq = (const float*)d_in[1];
    const float* bq = (const float*)d_in[2];
    const float* Wk = (const float*)d_in[3];
    const float* bk = (const float*)d_in[4];
    const float* Wv = (const float*)d_in[5];
    const float* bv = (const float*)d_in[6];
    float* out = (float*)d_out;
    char* ws = (char*)d_ws;
    const size_t MB = 1u << 20;

    // layout (236 MB):
    // [0,6) Wth[3]  [6,12) Wtl[3]
    // [12,76) X region: Xh|Xl during projections; Sb f32 [4][S][S] after (P in-place)
    // [76,108) Qh  [108,140) Ql  [140,172) Kh  [172,204) Kl  [204,236) Vt bf16
    __bf16* Wth = (__bf16*)ws;          __bf16* Wtl = (__bf16*)(ws + 6 * MB);
    __bf16* Xh = (__bf16*)(ws + 12 * MB);  __bf16* Xl = (__bf16*)(ws + 44 * MB);
    __bf16* Qh = (__bf16*)(ws + 76 * MB);  __bf16* Ql = (__bf16*)(ws + 108 * MB);
    __bf16* Kh = (__bf16*)(ws + 140 * MB); __bf16* Kl = (__bf16*)(ws + 172 * MB);
    __bf16* Vt = (__bf16*)(ws + 204 * MB);
    float*  Sb = (float*)(ws + 12 * MB);   // [4][S][S] f32; P bf16 in-place

    const int LDS_T3 = 131072;             // 64K A + 2x32K B
    const int LDS_T1 = 98304;              // 64K A + 2x16K B
    hipFuncSetAttribute(reinterpret_cast<const void*>(&bgemm256<3, CM_SPLIT, 256>),
                        hipFuncAttributeMaxDynamicSharedMemorySize, LDS_T3);
    hipFuncSetAttribute(reinterpret_cast<const void*>(&bgemm256<3, CM_TRANSV, 256>),
                        hipFuncAttributeMaxDynamicSharedMemorySize, LDS_T3);
    hipFuncSetAttribute(reinterpret_cast<const void*>(&bgemm256<3, CM_F32, 256>),
                        hipFuncAttributeMaxDynamicSharedMemorySize, LDS_T3);
    hipFuncSetAttribute(reinterpret_cast<const void*>(&bgemm256<1, CM_F32, 128>),
                        hipFuncAttributeMaxDynamicSharedMemorySize, LDS_T1);

    // 1) split inputs to bf16 hi/lo planes
    xsplit<<<dim3(16384), 256, 0, stream>>>(X, Xh, Xl);
    wsplit<<<dim3(32, 32, 3), dim3(32, 8), 0, stream>>>(Wq, Wk, Wv, Wth, Wtl);

    // 2) projections (3-term split GEMM)
    const long MW = 1024 * 1024;
    bgemm256<3, CM_SPLIT, 256><<<dim3(D / 256, 64, 1), 512, LDS_T3, stream>>>(
        Xh, Xl, 0, Wth, Wtl, 0, D, D, Qh, Ql, D, 0, bq, D);
    bgemm256<3, CM_SPLIT, 256><<<dim3(D / 256, 64, 1), 512, LDS_T3, stream>>>(
        Xh, Xl, 0, Wth + MW, Wtl + MW, 0, D, D, Kh, Kl, D, 0, bk, D);
    bgemm256<3, CM_TRANSV, 256><<<dim3(D / 256, 64, 1), 512, LDS_T3, stream>>>(
        Xh, Xl, 0, Wth + 2 * MW, Wtl + 2 * MW, 0, D, D, Vt, nullptr, 0, 0, bv, D);

    // 3) per 4-batch group: scores -> in-place softmax->bf16 P -> PV
    for (int g = 0; g < 2; ++g) {
        const int b0 = g * 4;
        bgemm256<3, CM_F32, 256><<<dim3(S / 256, S / 256, 4), 512, LDS_T3, stream>>>(
            Qh + (long)b0 * S * D, Ql + (long)b0 * S * D, (long)S * D,
            Kh + (long)b0 * S * D, Kl + (long)b0 * S * D, (long)S * D,
            D, D, Sb, nullptr, S, (long)S * S, nullptr, D);
        pconv<<<dim3(4 * S), 256, 0, stream>>>(Sb);
        // PV: A = bf16 P rows embedded in f32 buffer (lda = 2S bf16 elements)
        bgemm256<1, CM_F32, 128><<<dim3(D / 128, S / 256, 4), 512, LDS_T1, stream>>>(
            (const __bf16*)Sb, nullptr, 2L * S * S,
            Vt + (long)b0 * D * S, nullptr, (long)D * S,
            2 * S, S, out + (long)b0 * S * D, nullptr, D, (long)S * D, nullptr, S);
    }
}

// Round 8
// 589.041 us; speedup vs baseline: 1.9992x; 1.0491x over previous
//
#include <hip/hip_runtime.h>
#include <hip/hip_bf16.h>

// B=8, S=2048, D=1024, fp32 in/out.
static constexpr int S = 2048;
static constexpr int D = 1024;
static constexpr int NB = 8;

#define LOG2E 1.4426950408889634f

typedef float  f32x4  __attribute__((ext_vector_type(4)));
typedef __bf16 bf16x4 __attribute__((ext_vector_type(4)));
typedef __bf16 bf16x8 __attribute__((ext_vector_type(8)));

#define CM_F32    0
#define CM_SPLIT  1
#define CM_TRANSV 2

#define GLD16(g, l) __builtin_amdgcn_global_load_lds(                         \
    (const __attribute__((address_space(1))) void*)(g),                       \
    (__attribute__((address_space(3))) void*)(l), 16, 0, 0)

#define MFMA16(a, b, c) __builtin_amdgcn_mfma_f32_16x16x32_bf16((a), (b), (c), 0, 0, 0)

// ---------------------------------------------------------------------------
// 256xBNT tile, 8 waves, 2-phase/tile pipelined K-loop, counted vmcnt,
// 2 barriers per K-tile. XCD-aware bijective block swizzle (T1/m204): blocks
// sharing operand panels land on the same XCD's L2.
//   TERMS==3: K-tile = 32 real k; chunks 0-3 = hi plane, 4-7 = lo plane.
//             ph0: acc += Ah*Bh (a0 kept in regs); ph1: acc += Ah*Bl + Al*Bh.
//   TERMS==1: K-tile = 64 k; chunks 0-7 = k 0..63.
//             ph0: acc += A(k0-31)*B(k0-31); ph1: acc += A(k32-63)*B(k32-63).
// LDS: A = 2 bufs x 32 KB at 0; B = 2 bufs x (BNT*128 B) at 64 KB.
// Swizzle (both sides, 0-conflict verified r5): LDS slot s of row r holds
// global chunk s^(r&7); stage reads global chunk (lane&7)^(lane>>3), LDS linear.
// All stage units for tile t+1 issue at t.ph0. Wait vmcnt(counted) at ph0;
// vmcnt(0) only on the last tile. End-of-tile: lgkmcnt(0)+sched_barrier+bar.
// ---------------------------------------------------------------------------
template <int TERMS, int CMODE, int BNT>
__global__ __launch_bounds__(512, 1) void bgemm256(
    const __bf16* __restrict__ Ah_, const __bf16* __restrict__ Al_, long sAz,
    const __bf16* __restrict__ Bh_, const __bf16* __restrict__ Bl_, long sBz,
    int lda, int ldb,
    void* __restrict__ C1, void* __restrict__ C2, int ldc, long sCz,
    const float* __restrict__ bias, int K)
{
    extern __shared__ char smem[];
    constexpr int NW_N = BNT / 64;        // waves along N
    constexpr int NW_M = 8 / NW_N;        // waves along M
    constexpr int WM   = 256 / NW_M;      // rows per wave tile
    constexpr int MI   = WM / 16;         // acc rows per wave
    constexpr int BBUF = BNT * 128;       // bytes per B buffer
    constexpr int BH   = BNT / 128;       // B stage halves (1 or 2)

    // ---- XCD-aware bijective block swizzle (T1, m204) ----
    // HW assigns wg -> XCD as (dispatch order % 8). Remap so each residue
    // class becomes a CONTIGUOUS chunk of consumed coordinates: panel-sharing
    // neighbors then co-reside on one XCD's L2.
    int bx, by, bz;
    {
        const int gx = gridDim.x, gy = gridDim.y;
        const int nwg = gx * gy * gridDim.z;
        const int wg = blockIdx.x + gx * (blockIdx.y + gy * blockIdx.z);
        const int q = nwg >> 3, r = nwg & 7;
        const int xcd = wg & 7, i = wg >> 3;
        const int nid = (xcd < r) ? xcd * (q + 1) + i
                                  : r * (q + 1) + (xcd - r) * q + i;
        bx = nid % gx;
        const int tmp = nid / gx;
        by = tmp % gy;
        bz = tmp / gy;
    }

    const int t = threadIdx.x;
    const int z = bz;
    const int m0 = by * 256;
    const int n0 = bx * BNT;
    const int lane = t & 63, wid = t >> 6;
    const int wr = wid / NW_N, wc = wid % NW_N;
    const int fr = lane & 15, fq = lane >> 4;
    const int srow = lane >> 3;                 // 0..7
    const int schunk = (lane & 7) ^ srow;       // swizzled global chunk 0..7
    const int rowbase = wid * 8 + srow;

    const __bf16* Ahz = Ah_ + (long)z * sAz;
    const __bf16* Alz = (TERMS == 3) ? Al_ + (long)z * sAz : nullptr;
    const __bf16* Bhz = Bh_ + (long)z * sBz;
    const __bf16* Blz = (TERMS == 3) ? Bl_ + (long)z * sBz : nullptr;

    auto stA = [&](int tile, int h) {
        const long kk = (TERMS == 3) ? (long)tile * 32 + (schunk & 3) * 8
                                     : (long)tile * 64 + schunk * 8;
        const __bf16* plane = (TERMS == 3 && schunk >= 4) ? Alz : Ahz;
        char* lbase = smem + (tile & 1) * 32768 + (h * 128 + wid * 8) * 128;
#pragma unroll
        for (int i = 0; i < 2; ++i)
            GLD16(plane + (long)(m0 + h * 128 + i * 64 + rowbase) * lda + kk,
                  lbase + i * 8192);
    };
    auto stB = [&](int tile, int h) {
        const long kk = (TERMS == 3) ? (long)tile * 32 + (schunk & 3) * 8
                                     : (long)tile * 64 + schunk * 8;
        const __bf16* plane = (TERMS == 3 && schunk >= 4) ? Blz : Bhz;
        char* lbase = smem + 65536 + (tile & 1) * BBUF + (h * 128 + wid * 8) * 128;
#pragma unroll
        for (int i = 0; i < 2; ++i)
            GLD16(plane + (long)(n0 + h * 128 + i * 64 + rowbase) * ldb + kk,
                  lbase + i * 8192);
    };
    auto rdA = [&](int buf, int c, int mi) -> bf16x8 {
        const int row = wr * WM + mi * 16 + fr;
        return *(const bf16x8*)(smem + buf * 32768 + row * 128 +
                                ((c ^ (row & 7)) << 4));
    };
    auto rdB = [&](int buf, int c, int ni) -> bf16x8 {
        const int row = wc * 64 + ni * 16 + fr;
        return *(const bf16x8*)(smem + 65536 + buf * BBUF + row * 128 +
                                ((c ^ (row & 7)) << 4));
    };

    f32x4 acc[MI][4] = {};
    const int ktiles = K / ((TERMS == 3) ? 32 : 64);

    // prologue: stage tile 0 (same unit order as in-loop issue order)
    stA(0, 0); stA(0, 1); stB(0, 0);
    if (BH == 2) stB(0, 1);

    for (int tt = 0; tt < ktiles; ++tt) {
        const int buf = tt & 1;
        const bool pf = (tt + 1 < ktiles);
        bf16x8 a0[MI], b0[4], b1[4];

        // ---------------- phase 0: slot0 (chunk fq), all mi ----------------
        if (pf) {
            stA(tt + 1, 0); stA(tt + 1, 1); stB(tt + 1, 0);
            if (BH == 2) stB(tt + 1, 1);
            if (BH == 2) asm volatile("s_waitcnt vmcnt(8)" ::: "memory");
            else         asm volatile("s_waitcnt vmcnt(6)" ::: "memory");
        } else {
            asm volatile("s_waitcnt vmcnt(0)" ::: "memory");
        }
        __builtin_amdgcn_s_barrier();
#pragma unroll
        for (int ni = 0; ni < 4; ++ni) b0[ni] = rdB(buf, fq, ni);
#pragma unroll
        for (int mi = 0; mi < MI; ++mi) a0[mi] = rdA(buf, fq, mi);
        __builtin_amdgcn_s_setprio(1);
#pragma unroll
        for (int mi = 0; mi < MI; ++mi)
#pragma unroll
            for (int ni = 0; ni < 4; ++ni)
                acc[mi][ni] = MFMA16(a0[mi], b0[ni], acc[mi][ni]);
        __builtin_amdgcn_s_setprio(0);

        // ---------------- phase 1: slot1 (chunk 4+fq), all mi ----------------
        // (no barrier needed: same buf, staged before tile start)
#pragma unroll
        for (int ni = 0; ni < 4; ++ni) b1[ni] = rdB(buf, 4 + fq, ni);
        __builtin_amdgcn_s_setprio(1);
#pragma unroll
        for (int mi = 0; mi < MI; ++mi) {
            const bf16x8 a1 = rdA(buf, 4 + fq, mi);
#pragma unroll
            for (int ni = 0; ni < 4; ++ni) {
                if (TERMS == 3) {
                    acc[mi][ni] = MFMA16(a0[mi], b1[ni], acc[mi][ni]);  // hi*lo
                    acc[mi][ni] = MFMA16(a1, b0[ni], acc[mi][ni]);      // lo*hi
                } else {
                    acc[mi][ni] = MFMA16(a1, b1[ni], acc[mi][ni]);      // k-half 1
                }
            }
        }
        __builtin_amdgcn_s_setprio(0);
        // all reads of buf must have landed before tile t+1 restages it
        asm volatile("s_waitcnt lgkmcnt(0)" ::: "memory");
        __builtin_amdgcn_sched_barrier(0);
        __builtin_amdgcn_s_barrier();
    }

    // ---------------- epilogue ----------------
#pragma unroll
    for (int mi = 0; mi < MI; ++mi) {
        const int rbase = m0 + wr * WM + mi * 16 + fq * 4;
#pragma unroll
        for (int ni = 0; ni < 4; ++ni) {
            const int col = n0 + wc * 64 + ni * 16 + fr;
            f32x4 a = acc[mi][ni];
            if (CMODE != CM_F32) {
                const float bv = bias[col];
#pragma unroll
                for (int j = 0; j < 4; ++j) a[j] += bv;
            }
            if (CMODE == CM_F32) {
                float* C = (float*)C1 + (long)z * sCz;
#pragma unroll
                for (int j = 0; j < 4; ++j)
                    C[(long)(rbase + j) * ldc + col] = a[j];
            } else if (CMODE == CM_SPLIT) {
                __bf16* Ch = (__bf16*)C1;
                __bf16* Cl = (__bf16*)C2;
#pragma unroll
                for (int j = 0; j < 4; ++j) {
                    const float q = a[j];
                    const __bf16 h = (__bf16)q;
                    Ch[(long)(rbase + j) * ldc + col] = h;
                    Cl[(long)(rbase + j) * ldc + col] = (__bf16)(q - (float)h);
                }
            } else {  // CM_TRANSV: Vt[b][col][s] bf16
                const int b_ = rbase >> 11;
                const int s_ = rbase & (S - 1);
                bf16x4 h;
#pragma unroll
                for (int j = 0; j < 4; ++j) h[j] = (__bf16)a[j];
                *(bf16x4*)((__bf16*)C1 + ((long)b_ * D + col) * S + s_) = h;
            }
        }
    }
}

// ---------------------------------------------------------------------------
__global__ __launch_bounds__(256) void xsplit(
    const float* __restrict__ X, __bf16* __restrict__ Xh, __bf16* __restrict__ Xl)
{
    const long i = ((long)blockIdx.x * 256 + threadIdx.x) * 4;
    f32x4 v = *(const f32x4*)(X + i);
    bf16x4 h, l;
#pragma unroll
    for (int j = 0; j < 4; ++j) {
        h[j] = (__bf16)v[j];
        l[j] = (__bf16)(v[j] - (float)h[j]);
    }
    *(bf16x4*)(Xh + i) = h;
    *(bf16x4*)(Xl + i) = l;
}

// ---------------------------------------------------------------------------
__global__ void wsplit(const float* __restrict__ W0, const float* __restrict__ W1,
                       const float* __restrict__ W2,
                       __bf16* __restrict__ Th, __bf16* __restrict__ Tl)
{
    const float* W = blockIdx.z == 0 ? W0 : (blockIdx.z == 1 ? W1 : W2);
    __bf16* th = Th + (long)blockIdx.z * 1024 * 1024;
    __bf16* tl = Tl + (long)blockIdx.z * 1024 * 1024;
    __shared__ float tile[32][33];
    const int bx = blockIdx.x * 32, by = blockIdx.y * 32;
    const int tx = threadIdx.x, ty = threadIdx.y;
#pragma unroll
    for (int i = ty; i < 32; i += 8) tile[i][tx] = W[(long)(by + i) * 1024 + bx + tx];
    __syncthreads();
#pragma unroll
    for (int i = ty; i < 32; i += 8) {
        const float v = tile[tx][i];
        const __bf16 h = (__bf16)v;
        th[(long)(bx + i) * 1024 + by + tx] = h;
        tl[(long)(bx + i) * 1024 + by + tx] = (__bf16)(v - (float)h);
    }
}

// ---------------------------------------------------------------------------
// Fused row softmax: read f32 score row, write P = exp(s-m)/l as bf16
// IN-PLACE into the start of the row's f32 storage.
// ---------------------------------------------------------------------------
__global__ __launch_bounds__(256) void pconv(float* __restrict__ Sb)
{
    const long row = blockIdx.x;
    float* p = Sb + row * (long)S;
    const int t = threadIdx.x;

    f32x4 x0 = *(const f32x4*)(p + t * 8);
    f32x4 x1 = *(const f32x4*)(p + t * 8 + 4);

    float m = -3.4e38f;
#pragma unroll
    for (int j = 0; j < 4; ++j) m = fmaxf(m, fmaxf(x0[j], x1[j]));
#pragma unroll
    for (int o = 32; o >= 1; o >>= 1) m = fmaxf(m, __shfl_xor(m, o));

    __shared__ float wm[4], wsum[4];
    const int wid = t >> 6, lane = t & 63;
    if (lane == 0) wm[wid] = m;
    __syncthreads();
    m = fmaxf(fmaxf(wm[0], wm[1]), fmaxf(wm[2], wm[3]));

    float e[8], ssum = 0.f;
#pragma unroll
    for (int j = 0; j < 4; ++j) {
        e[j]     = exp2f((x0[j] - m) * LOG2E);
        e[4 + j] = exp2f((x1[j] - m) * LOG2E);
        ssum += e[j] + e[4 + j];
    }
#pragma unroll
    for (int o = 32; o >= 1; o >>= 1) ssum += __shfl_xor(ssum, o);
    if (lane == 0) wsum[wid] = ssum;
    __syncthreads();
    const float invl = 1.0f / (wsum[0] + wsum[1] + wsum[2] + wsum[3]);

    bf16x8 outv;
#pragma unroll
    for (int j = 0; j < 8; ++j) outv[j] = (__bf16)(e[j] * invl);
    *(bf16x8*)((__bf16*)p + t * 8) = outv;
}

// ---------------------------------------------------------------------------
extern "C" void kernel_launch(void* const* d_in, const int* in_sizes, int n_in,
                              void* d_out, int out_size, void* d_ws, size_t ws_size,
                              hipStream_t stream)
{
    const float* X  = (const float*)d_in[0];
    const float* Wq = (const float*)d_in[1];
    const float* bq = (const float*)d_in[2];
    const float* Wk = (const float*)d_in[3];
    const float* bk = (const float*)d_in[4];
    const float* Wv = (const float*)d_in[5];
    const float* bv = (const float*)d_in[6];
    float* out = (float*)d_out;
    char* ws = (char*)d_ws;
    const size_t MB = 1u << 20;

    // layout (236 MB):
    // [0,6) Wth[3]  [6,12) Wtl[3]
    // [12,76) X region: Xh|Xl during projections; Sb f32 [4][S][S] after (P in-place)
    // [76,108) Qh  [108,140) Ql  [140,172) Kh  [172,204) Kl  [204,236) Vt bf16
    __bf16* Wth = (__bf16*)ws;          __bf16* Wtl = (__bf16*)(ws + 6 * MB);
    __bf16* Xh = (__bf16*)(ws + 12 * MB);  __bf16* Xl = (__bf16*)(ws + 44 * MB);
    __bf16* Qh = (__bf16*)(ws + 76 * MB);  __bf16* Ql = (__bf16*)(ws + 108 * MB);
    __bf16* Kh = (__bf16*)(ws + 140 * MB); __bf16* Kl = (__bf16*)(ws + 172 * MB);
    __bf16* Vt = (__bf16*)(ws + 204 * MB);
    float*  Sb = (float*)(ws + 12 * MB);   // [4][S][S] f32; P bf16 in-place

    const int LDS_T3 = 131072;             // 64K A + 2x32K B
    const int LDS_T1 = 98304;              // 64K A + 2x16K B
    hipFuncSetAttribute(reinterpret_cast<const void*>(&bgemm256<3, CM_SPLIT, 256>),
                        hipFuncAttributeMaxDynamicSharedMemorySize, LDS_T3);
    hipFuncSetAttribute(reinterpret_cast<const void*>(&bgemm256<3, CM_TRANSV, 256>),
                        hipFuncAttributeMaxDynamicSharedMemorySize, LDS_T3);
    hipFuncSetAttribute(reinterpret_cast<const void*>(&bgemm256<3, CM_F32, 256>),
                        hipFuncAttributeMaxDynamicSharedMemorySize, LDS_T3);
    hipFuncSetAttribute(reinterpret_cast<const void*>(&bgemm256<1, CM_F32, 128>),
                        hipFuncAttributeMaxDynamicSharedMemorySize, LDS_T1);

    // 1) split inputs to bf16 hi/lo planes
    xsplit<<<dim3(16384), 256, 0, stream>>>(X, Xh, Xl);
    wsplit<<<dim3(32, 32, 3), dim3(32, 8), 0, stream>>>(Wq, Wk, Wv, Wth, Wtl);

    // 2) projections (3-term split GEMM)
    const long MW = 1024 * 1024;
    bgemm256<3, CM_SPLIT, 256><<<dim3(D / 256, 64, 1), 512, LDS_T3, stream>>>(
        Xh, Xl, 0, Wth, Wtl, 0, D, D, Qh, Ql, D, 0, bq, D);
    bgemm256<3, CM_SPLIT, 256><<<dim3(D / 256, 64, 1), 512, LDS_T3, stream>>>(
        Xh, Xl, 0, Wth + MW, Wtl + MW, 0, D, D, Kh, Kl, D, 0, bk, D);
    bgemm256<3, CM_TRANSV, 256><<<dim3(D / 256, 64, 1), 512, LDS_T3, stream>>>(
        Xh, Xl, 0, Wth + 2 * MW, Wtl + 2 * MW, 0, D, D, Vt, nullptr, 0, 0, bv, D);

    // 3) per 4-batch group: scores -> in-place softmax->bf16 P -> PV
    for (int g = 0; g < 2; ++g) {
        const int b0 = g * 4;
        bgemm256<3, CM_F32, 256><<<dim3(S / 256, S / 256, 4), 512, LDS_T3, stream>>>(
            Qh + (long)b0 * S * D, Ql + (long)b0 * S * D, (long)S * D,
            Kh + (long)b0 * S * D, Kl + (long)b0 * S * D, (long)S * D,
            D, D, Sb, nullptr, S, (long)S * S, nullptr, D);
        pconv<<<dim3(4 * S), 256, 0, stream>>>(Sb);
        // PV: A = bf16 P rows embedded in f32 buffer (lda = 2S bf16 elements)
        bgemm256<1, CM_F32, 128><<<dim3(D / 128, S / 256, 4), 512, LDS_T1, stream>>>(
            (const __bf16*)Sb, nullptr, 2L * S * S,
            Vt + (long)b0 * D * S, nullptr, (long)D * S,
            2 * S, S, out + (long)b0 * S * D, nullptr, D, (long)S * D, nullptr, S);
    }
}

// Round 9
// 569.978 us; speedup vs baseline: 2.0661x; 1.0334x over previous
//
#include <hip/hip_runtime.h>
#include <hip/hip_bf16.h>

// B=8, S=2048, D=1024, fp32 in/out.
static constexpr int S = 2048;
static constexpr int D = 1024;
static constexpr int NB = 8;

#define LOG2E 1.4426950408889634f

typedef float  f32x4  __attribute__((ext_vector_type(4)));
typedef __bf16 bf16x4 __attribute__((ext_vector_type(4)));
typedef __bf16 bf16x8 __attribute__((ext_vector_type(8)));

#define CM_F32    0
#define CM_SPLIT  1
#define CM_TRANSV 2

#define GLD16(g, l) __builtin_amdgcn_global_load_lds(                         \
    (const __attribute__((address_space(1))) void*)(g),                       \
    (__attribute__((address_space(3))) void*)(l), 16, 0, 0)

#define MFMA16(a, b, c) __builtin_amdgcn_mfma_f32_16x16x32_bf16((a), (b), (c), 0, 0, 0)
#define BAR() __builtin_amdgcn_s_barrier()
#define PRIO1() __builtin_amdgcn_s_setprio(1)
#define PRIO0() __builtin_amdgcn_s_setprio(0)

// ---------------------------------------------------------------------------
// 256xBNT tile, 8 waves, m201-style fine-phase pipelined K-loop.
// Each phase: {pre: ds_reads for a LATER phase + 1 stage unit}; bar; counted
// lgkmcnt; setprio(1); 16 MFMA; setprio(0); bar. Reads retire >=1 phase after
// issue -> lgkm waits are ~free; MFMA regions are pure (no LDS ops inside).
//   TERMS==3 (BNT=256): K-tile = 32 real k (chunks 0-3 hi, 4-7 lo), 6 phases:
//     M0 aA(hi,0-3)*b0(hi)   M1 aB(hi,4-7)*b0   M2 aA*b1(lo)
//     M3 aB*b1               M4 aA2(lo,0-3)*b0  M5 aB2(lo,4-7)*b0
//   TERMS==1 (BNT=128): K-tile = 64 k, 2 phases: M0 a0*b0(k0-31), M1 a1*b1.
// Buffer seal: vmcnt(0)+bar at last phase (exact-counted: only next tile's
// loads outstanding); next tile's first frag reads issued in the seal tail.
// LDS chunk-XOR swizzle both sides (0-conflict, r5-verified). XCD-bijective
// block swizzle (T1/m204) kept from r8 (FETCH 135->49 MB).
// ---------------------------------------------------------------------------
template <int TERMS, int CMODE, int BNT>
__global__ __launch_bounds__(512, 1) void bgemm256(
    const __bf16* __restrict__ Ah_, const __bf16* __restrict__ Al_, long sAz,
    const __bf16* __restrict__ Bh_, const __bf16* __restrict__ Bl_, long sBz,
    int lda, int ldb,
    void* __restrict__ C1, void* __restrict__ C2, int ldc, long sCz,
    const float* __restrict__ bias, int K)
{
    extern __shared__ char smem[];
    constexpr int NW_N = BNT / 64;        // waves along N
    constexpr int NW_M = 8 / NW_N;        // waves along M
    constexpr int WM   = 256 / NW_M;      // rows per wave tile
    constexpr int MI   = WM / 16;         // acc rows per wave
    constexpr int BBUF = BNT * 128;       // bytes per B buffer

    // ---- XCD-aware bijective block swizzle (T1, m204) ----
    int bx, by, bz;
    {
        const int gx = gridDim.x, gy = gridDim.y;
        const int nwg = gx * gy * gridDim.z;
        const int wg = blockIdx.x + gx * (blockIdx.y + gy * blockIdx.z);
        const int q = nwg >> 3, r = nwg & 7;
        const int xcd = wg & 7, i = wg >> 3;
        const int nid = (xcd < r) ? xcd * (q + 1) + i
                                  : r * (q + 1) + (xcd - r) * q + i;
        bx = nid % gx;
        const int tmp = nid / gx;
        by = tmp % gy;
        bz = tmp / gy;
    }

    const int t = threadIdx.x;
    const int z = bz;
    const int m0 = by * 256;
    const int n0 = bx * BNT;
    const int lane = t & 63, wid = t >> 6;
    const int wr = wid / NW_N, wc = wid % NW_N;
    const int fr = lane & 15, fq = lane >> 4;
    const int srow = lane >> 3;                 // 0..7
    const int schunk = (lane & 7) ^ srow;       // swizzled global chunk 0..7
    const int rowbase = wid * 8 + srow;

    const __bf16* Ahz = Ah_ + (long)z * sAz;
    const __bf16* Alz = (TERMS == 3) ? Al_ + (long)z * sAz : nullptr;
    const __bf16* Bhz = Bh_ + (long)z * sBz;
    const __bf16* Blz = (TERMS == 3) ? Bl_ + (long)z * sBz : nullptr;

    auto stA = [&](int tile, int h) {
        const long kk = (TERMS == 3) ? (long)tile * 32 + (schunk & 3) * 8
                                     : (long)tile * 64 + schunk * 8;
        const __bf16* plane = (TERMS == 3 && schunk >= 4) ? Alz : Ahz;
        char* lbase = smem + (tile & 1) * 32768 + (h * 128 + wid * 8) * 128;
#pragma unroll
        for (int i = 0; i < 2; ++i)
            GLD16(plane + (long)(m0 + h * 128 + i * 64 + rowbase) * lda + kk,
                  lbase + i * 8192);
    };
    auto stB = [&](int tile, int h) {
        const long kk = (TERMS == 3) ? (long)tile * 32 + (schunk & 3) * 8
                                     : (long)tile * 64 + schunk * 8;
        const __bf16* plane = (TERMS == 3 && schunk >= 4) ? Blz : Bhz;
        char* lbase = smem + 65536 + (tile & 1) * BBUF + (h * 128 + wid * 8) * 128;
#pragma unroll
        for (int i = 0; i < 2; ++i)
            GLD16(plane + (long)(n0 + h * 128 + i * 64 + rowbase) * ldb + kk,
                  lbase + i * 8192);
    };
    auto rdA = [&](int buf, int c, int mi) -> bf16x8 {
        const int row = wr * WM + mi * 16 + fr;
        return *(const bf16x8*)(smem + buf * 32768 + row * 128 +
                                ((c ^ (row & 7)) << 4));
    };
    auto rdB = [&](int buf, int c, int ni) -> bf16x8 {
        const int row = wc * 64 + ni * 16 + fr;
        return *(const bf16x8*)(smem + 65536 + buf * BBUF + row * 128 +
                                ((c ^ (row & 7)) << 4));
    };

    f32x4 acc[MI][4] = {};
    const int ktiles = K / ((TERMS == 3) ? 32 : 64);

    if constexpr (TERMS == 3) {
        bf16x8 b0[4], b1[4], aA[4], aB[4], aA2[4], aB2[4];
        auto mb = [&](int base, bf16x8 (&A)[4], bf16x8 (&B)[4]) {
#pragma unroll
            for (int mi = 0; mi < 4; ++mi)
#pragma unroll
                for (int ni = 0; ni < 4; ++ni)
                    acc[base + mi][ni] = MFMA16(A[mi], B[ni], acc[base + mi][ni]);
        };
        // prologue: stage tile 0, seal, pre-read M0/M1 fragments
        stA(0, 0); stA(0, 1); stB(0, 0); stB(0, 1);
        asm volatile("s_waitcnt vmcnt(0)" ::: "memory");
        BAR();
#pragma unroll
        for (int ni = 0; ni < 4; ++ni) b0[ni] = rdB(0, fq, ni);
#pragma unroll
        for (int mi = 0; mi < 4; ++mi) aA[mi] = rdA(0, fq, mi);
#pragma unroll
        for (int mi = 0; mi < 4; ++mi) aB[mi] = rdA(0, fq, 4 + mi);

        for (int tt = 0; tt < ktiles; ++tt) {
            const int buf = tt & 1;
            const bool pf = (tt + 1 < ktiles);
            // ---- P0: M0 = aA·b0 (outstanding: b0,aA,aB(12) -> wait first 8) ----
            if (pf) stA(tt + 1, 0);
            BAR();
            asm volatile("s_waitcnt lgkmcnt(4)" ::: "memory");
            PRIO1(); mb(0, aA, b0); PRIO0();
            BAR();
            // ---- P1: pre-read b1 (for M2); M1 = aB·b0 (wait aB, allow b1) ----
#pragma unroll
            for (int ni = 0; ni < 4; ++ni) b1[ni] = rdB(buf, 4 + fq, ni);
            if (pf) stA(tt + 1, 1);
            BAR();
            asm volatile("s_waitcnt lgkmcnt(4)" ::: "memory");
            PRIO1(); mb(4, aB, b0); PRIO0();
            BAR();
            // ---- P2: pre-read aA2 (for M4); M2 = aA·b1 (wait b1, allow aA2) ----
#pragma unroll
            for (int mi = 0; mi < 4; ++mi) aA2[mi] = rdA(buf, 4 + fq, mi);
            if (pf) stB(tt + 1, 0);
            BAR();
            asm volatile("s_waitcnt lgkmcnt(4)" ::: "memory");
            PRIO1(); mb(0, aA, b1); PRIO0();
            BAR();
            // ---- P3: pre-read aB2 (for M5); M3 = aB·b1 (srcs already waited) ----
#pragma unroll
            for (int mi = 0; mi < 4; ++mi) aB2[mi] = rdA(buf, 4 + fq, 4 + mi);
            if (pf) stB(tt + 1, 1);
            BAR();
            PRIO1(); mb(4, aB, b1); PRIO0();
            BAR();
            // ---- P4: M4 = aA2·b0 (wait aA2, allow aB2) ----
            asm volatile("s_waitcnt lgkmcnt(4)" ::: "memory");
            PRIO1(); mb(0, aA2, b0); PRIO0();
            BAR();
            // ---- P5: seal next buf; M5 = aB2·b0; tail-read next tile's frags ----
            asm volatile("s_waitcnt vmcnt(0)" ::: "memory");
            BAR();   // buf^1 sealed for tile tt+1
            asm volatile("s_waitcnt lgkmcnt(0)" ::: "memory");
            PRIO1(); mb(4, aB2, b0); PRIO0();
            if (pf) {
                const int nb = buf ^ 1;
#pragma unroll
                for (int ni = 0; ni < 4; ++ni) b0[ni] = rdB(nb, fq, ni);
#pragma unroll
                for (int mi = 0; mi < 4; ++mi) aA[mi] = rdA(nb, fq, mi);
#pragma unroll
                for (int mi = 0; mi < 4; ++mi) aB[mi] = rdA(nb, fq, 4 + mi);
            }
        }
    } else {  // TERMS == 1 (PV, BNT=128, MI=4)
        bf16x8 b0[4], b1[4], a0[4], a1[4];
        auto mb = [&](bf16x8 (&A)[4], bf16x8 (&B)[4]) {
#pragma unroll
            for (int mi = 0; mi < 4; ++mi)
#pragma unroll
                for (int ni = 0; ni < 4; ++ni)
                    acc[mi][ni] = MFMA16(A[mi], B[ni], acc[mi][ni]);
        };
        stA(0, 0); stA(0, 1); stB(0, 0);
        asm volatile("s_waitcnt vmcnt(0)" ::: "memory");
        BAR();
#pragma unroll
        for (int ni = 0; ni < 4; ++ni) b0[ni] = rdB(0, fq, ni);
#pragma unroll
        for (int mi = 0; mi < 4; ++mi) a0[mi] = rdA(0, fq, mi);

        for (int tt = 0; tt < ktiles; ++tt) {
            const int buf = tt & 1;
            const bool pf = (tt + 1 < ktiles);
            // ---- P0: pre-read slot1 frags; M0 = a0·b0 (wait first 8) ----
#pragma unroll
            for (int ni = 0; ni < 4; ++ni) b1[ni] = rdB(buf, 4 + fq, ni);
#pragma unroll
            for (int mi = 0; mi < 4; ++mi) a1[mi] = rdA(buf, 4 + fq, mi);
            if (pf) { stA(tt + 1, 0); stA(tt + 1, 1); stB(tt + 1, 0); }
            BAR();
            asm volatile("s_waitcnt lgkmcnt(8)" ::: "memory");
            PRIO1(); mb(a0, b0); PRIO0();
            BAR();
            // ---- P1: M1 = a1·b1; seal; tail-read next slot0 ----
            asm volatile("s_waitcnt lgkmcnt(0)" ::: "memory");
            PRIO1(); mb(a1, b1); PRIO0();
            asm volatile("s_waitcnt vmcnt(0)" ::: "memory");
            BAR();   // buf^1 sealed
            if (pf) {
                const int nb = buf ^ 1;
#pragma unroll
                for (int ni = 0; ni < 4; ++ni) b0[ni] = rdB(nb, fq, ni);
#pragma unroll
                for (int mi = 0; mi < 4; ++mi) a0[mi] = rdA(nb, fq, mi);
            }
        }
    }

    // ---------------- epilogue ----------------
#pragma unroll
    for (int mi = 0; mi < MI; ++mi) {
        const int rbase = m0 + wr * WM + mi * 16 + fq * 4;
#pragma unroll
        for (int ni = 0; ni < 4; ++ni) {
            const int col = n0 + wc * 64 + ni * 16 + fr;
            f32x4 a = acc[mi][ni];
            if (CMODE != CM_F32) {
                const float bv = bias[col];
#pragma unroll
                for (int j = 0; j < 4; ++j) a[j] += bv;
            }
            if (CMODE == CM_F32) {
                float* C = (float*)C1 + (long)z * sCz;
#pragma unroll
                for (int j = 0; j < 4; ++j)
                    C[(long)(rbase + j) * ldc + col] = a[j];
            } else if (CMODE == CM_SPLIT) {
                __bf16* Ch = (__bf16*)C1;
                __bf16* Cl = (__bf16*)C2;
#pragma unroll
                for (int j = 0; j < 4; ++j) {
                    const float q = a[j];
                    const __bf16 h = (__bf16)q;
                    Ch[(long)(rbase + j) * ldc + col] = h;
                    Cl[(long)(rbase + j) * ldc + col] = (__bf16)(q - (float)h);
                }
            } else {  // CM_TRANSV: Vt[b][col][s] bf16
                const int b_ = rbase >> 11;
                const int s_ = rbase & (S - 1);
                bf16x4 h;
#pragma unroll
                for (int j = 0; j < 4; ++j) h[j] = (__bf16)a[j];
                *(bf16x4*)((__bf16*)C1 + ((long)b_ * D + col) * S + s_) = h;
            }
        }
    }
}

// ---------------------------------------------------------------------------
__global__ __launch_bounds__(256) void xsplit(
    const float* __restrict__ X, __bf16* __restrict__ Xh, __bf16* __restrict__ Xl)
{
    const long i = ((long)blockIdx.x * 256 + threadIdx.x) * 4;
    f32x4 v = *(const f32x4*)(X + i);
    bf16x4 h, l;
#pragma unroll
    for (int j = 0; j < 4; ++j) {
        h[j] = (__bf16)v[j];
        l[j] = (__bf16)(v[j] - (float)h[j]);
    }
    *(bf16x4*)(Xh + i) = h;
    *(bf16x4*)(Xl + i) = l;
}

// ---------------------------------------------------------------------------
__global__ void wsplit(const float* __restrict__ W0, const float* __restrict__ W1,
                       const float* __restrict__ W2,
                       __bf16* __restrict__ Th, __bf16* __restrict__ Tl)
{
    const float* W = blockIdx.z == 0 ? W0 : (blockIdx.z == 1 ? W1 : W2);
    __bf16* th = Th + (long)blockIdx.z * 1024 * 1024;
    __bf16* tl = Tl + (long)blockIdx.z * 1024 * 1024;
    __shared__ float tile[32][33];
    const int bx = blockIdx.x * 32, by = blockIdx.y * 32;
    const int tx = threadIdx.x, ty = threadIdx.y;
#pragma unroll
    for (int i = ty; i < 32; i += 8) tile[i][tx] = W[(long)(by + i) * 1024 + bx + tx];
    __syncthreads();
#pragma unroll
    for (int i = ty; i < 32; i += 8) {
        const float v = tile[tx][i];
        const __bf16 h = (__bf16)v;
        th[(long)(bx + i) * 1024 + by + tx] = h;
        tl[(long)(bx + i) * 1024 + by + tx] = (__bf16)(v - (float)h);
    }
}

// ---------------------------------------------------------------------------
// Fused row softmax: read f32 score row, write P = exp(s-m)/l as bf16
// IN-PLACE into the start of the row's f32 storage.
// ---------------------------------------------------------------------------
__global__ __launch_bounds__(256) void pconv(float* __restrict__ Sb)
{
    const long row = blockIdx.x;
    float* p = Sb + row * (long)S;
    const int t = threadIdx.x;

    f32x4 x0 = *(const f32x4*)(p + t * 8);
    f32x4 x1 = *(const f32x4*)(p + t * 8 + 4);

    float m = -3.4e38f;
#pragma unroll
    for (int j = 0; j < 4; ++j) m = fmaxf(m, fmaxf(x0[j], x1[j]));
#pragma unroll
    for (int o = 32; o >= 1; o >>= 1) m = fmaxf(m, __shfl_xor(m, o));

    __shared__ float wm[4], wsum[4];
    const int wid = t >> 6, lane = t & 63;
    if (lane == 0) wm[wid] = m;
    __syncthreads();
    m = fmaxf(fmaxf(wm[0], wm[1]), fmaxf(wm[2], wm[3]));

    float e[8], ssum = 0.f;
#pragma unroll
    for (int j = 0; j < 4; ++j) {
        e[j]     = exp2f((x0[j] - m) * LOG2E);
        e[4 + j] = exp2f((x1[j] - m) * LOG2E);
        ssum += e[j] + e[4 + j];
    }
#pragma unroll
    for (int o = 32; o >= 1; o >>= 1) ssum += __shfl_xor(ssum, o);
    if (lane == 0) wsum[wid] = ssum;
    __syncthreads();
    const float invl = 1.0f / (wsum[0] + wsum[1] + wsum[2] + wsum[3]);

    bf16x8 outv;
#pragma unroll
    for (int j = 0; j < 8; ++j) outv[j] = (__bf16)(e[j] * invl);
    *(bf16x8*)((__bf16*)p + t * 8) = outv;
}

// ---------------------------------------------------------------------------
extern "C" void kernel_launch(void* const* d_in, const int* in_sizes, int n_in,
                              void* d_out, int out_size, void* d_ws, size_t ws_size,
                              hipStream_t stream)
{
    const float* X  = (const float*)d_in[0];
    const float* Wq = (const float*)d_in[1];
    const float* bq = (const float*)d_in[2];
    const float* Wk = (const float*)d_in[3];
    const float* bk = (const float*)d_in[4];
    const float* Wv = (const float*)d_in[5];
    const float* bv = (const float*)d_in[6];
    float* out = (float*)d_out;
    char* ws = (char*)d_ws;
    const size_t MB = 1u << 20;

    // layout (236 MB):
    // [0,6) Wth[3]  [6,12) Wtl[3]
    // [12,76) X region: Xh|Xl during projections; Sb f32 [4][S][S] after (P in-place)
    // [76,108) Qh  [108,140) Ql  [140,172) Kh  [172,204) Kl  [204,236) Vt bf16
    __bf16* Wth = (__bf16*)ws;          __bf16* Wtl = (__bf16*)(ws + 6 * MB);
    __bf16* Xh = (__bf16*)(ws + 12 * MB);  __bf16* Xl = (__bf16*)(ws + 44 * MB);
    __bf16* Qh = (__bf16*)(ws + 76 * MB);  __bf16* Ql = (__bf16*)(ws + 108 * MB);
    __bf16* Kh = (__bf16*)(ws + 140 * MB); __bf16* Kl = (__bf16*)(ws + 172 * MB);
    __bf16* Vt = (__bf16*)(ws + 204 * MB);
    float*  Sb = (float*)(ws + 12 * MB);   // [4][S][S] f32; P bf16 in-place

    const int LDS_T3 = 131072;             // 64K A + 2x32K B
    const int LDS_T1 = 98304;              // 64K A + 2x16K B
    hipFuncSetAttribute(reinterpret_cast<const void*>(&bgemm256<3, CM_SPLIT, 256>),
                        hipFuncAttributeMaxDynamicSharedMemorySize, LDS_T3);
    hipFuncSetAttribute(reinterpret_cast<const void*>(&bgemm256<3, CM_TRANSV, 256>),
                        hipFuncAttributeMaxDynamicSharedMemorySize, LDS_T3);
    hipFuncSetAttribute(reinterpret_cast<const void*>(&bgemm256<3, CM_F32, 256>),
                        hipFuncAttributeMaxDynamicSharedMemorySize, LDS_T3);
    hipFuncSetAttribute(reinterpret_cast<const void*>(&bgemm256<1, CM_F32, 128>),
                        hipFuncAttributeMaxDynamicSharedMemorySize, LDS_T1);

    // 1) split inputs to bf16 hi/lo planes
    xsplit<<<dim3(16384), 256, 0, stream>>>(X, Xh, Xl);
    wsplit<<<dim3(32, 32, 3), dim3(32, 8), 0, stream>>>(Wq, Wk, Wv, Wth, Wtl);

    // 2) projections (3-term split GEMM)
    const long MW = 1024 * 1024;
    bgemm256<3, CM_SPLIT, 256><<<dim3(D / 256, 64, 1), 512, LDS_T3, stream>>>(
        Xh, Xl, 0, Wth, Wtl, 0, D, D, Qh, Ql, D, 0, bq, D);
    bgemm256<3, CM_SPLIT, 256><<<dim3(D / 256, 64, 1), 512, LDS_T3, stream>>>(
        Xh, Xl, 0, Wth + MW, Wtl + MW, 0, D, D, Kh, Kl, D, 0, bk, D);
    bgemm256<3, CM_TRANSV, 256><<<dim3(D / 256, 64, 1), 512, LDS_T3, stream>>>(
        Xh, Xl, 0, Wth + 2 * MW, Wtl + 2 * MW, 0, D, D, Vt, nullptr, 0, 0, bv, D);

    // 3) per 4-batch group: scores -> in-place softmax->bf16 P -> PV
    for (int g = 0; g < 2; ++g) {
        const int b0 = g * 4;
        bgemm256<3, CM_F32, 256><<<dim3(S / 256, S / 256, 4), 512, LDS_T3, stream>>>(
            Qh + (long)b0 * S * D, Ql + (long)b0 * S * D, (long)S * D,
            Kh + (long)b0 * S * D, Kl + (long)b0 * S * D, (long)S * D,
            D, D, Sb, nullptr, S, (long)S * S, nullptr, D);
        pconv<<<dim3(4 * S), 256, 0, stream>>>(Sb);
        // PV: A = bf16 P rows embedded in f32 buffer (lda = 2S bf16 elements)
        bgemm256<1, CM_F32, 128><<<dim3(D / 128, S / 256, 4), 512, LDS_T1, stream>>>(
            (const __bf16*)Sb, nullptr, 2L * S * S,
            Vt + (long)b0 * D * S, nullptr, (long)D * S,
            2 * S, S, out + (long)b0 * S * D, nullptr, D, (long)S * D, nullptr, S);
    }
}